// Round 1
// baseline (649.610 us; speedup 1.0000x reference)
//
#include <hip/hip_runtime.h>
#include <hip/hip_bf16.h>
#include <math.h>

#define L_SEQ 2048
#define NB 2
#define DM 1024
#define NHEAD 16
#define HDIM 64
#define QKV_LD 3072

typedef __attribute__((ext_vector_type(8))) __bf16 bf16x8;
typedef __attribute__((ext_vector_type(4))) __bf16 bf16x4;
typedef __attribute__((ext_vector_type(4))) float f32x4;

__device__ __forceinline__ __bf16 f2b(float x) { return (__bf16)x; }

// ---------------- GEMM: C[M,N] = A[M,K] @ B[K,N]  (+bias, +gelu) ----------------
// EPI: 0 = none, 1 = +bias, 2 = +bias then exact gelu
template<int EPI>
__global__ __launch_bounds__(256) void gemm_k(const float* __restrict__ A,
                                              const float* __restrict__ B,
                                              const float* __restrict__ bias,
                                              float* __restrict__ C,
                                              int M, int N, int K) {
  __shared__ __bf16 As[128][40];   // [m][k], row stride 80B (16B aligned, 2-way bank alias)
  __shared__ __bf16 Bs[128][40];   // [n][k] transposed
  const int tid  = threadIdx.x;
  const int lane = tid & 63;
  const int wave = tid >> 6;
  const int wr = wave >> 1, wc = wave & 1;
  const int lr = lane & 15, lq = lane >> 4;
  const int bm0 = blockIdx.y * 128, bn0 = blockIdx.x * 128;
  f32x4 acc[4][4] = {};

  for (int k0 = 0; k0 < K; k0 += 32) {
    // stage A tile 128x32 (f32 -> bf16)
#pragma unroll
    for (int r = 0; r < 4; ++r) {
      int f = tid + 256 * r;
      int m = f >> 3, kq = f & 7;
      float4 v = *reinterpret_cast<const float4*>(A + (size_t)(bm0 + m) * K + k0 + kq * 4);
      bf16x4 w; w[0] = f2b(v.x); w[1] = f2b(v.y); w[2] = f2b(v.z); w[3] = f2b(v.w);
      *reinterpret_cast<bf16x4*>(&As[m][kq * 4]) = w;
    }
    // stage B tile 32x128 transposed -> Bs[n][k]
#pragma unroll
    for (int r = 0; r < 4; ++r) {
      int f = tid + 256 * r;
      int kk = f >> 5, nq = f & 31;
      float4 v = *reinterpret_cast<const float4*>(B + (size_t)(k0 + kk) * N + bn0 + nq * 4);
      Bs[nq * 4 + 0][kk] = f2b(v.x);
      Bs[nq * 4 + 1][kk] = f2b(v.y);
      Bs[nq * 4 + 2][kk] = f2b(v.z);
      Bs[nq * 4 + 3][kk] = f2b(v.w);
    }
    __syncthreads();

    bf16x8 af[4], bfr[4];
#pragma unroll
    for (int i = 0; i < 4; ++i)
      af[i] = *reinterpret_cast<const bf16x8*>(&As[wr * 64 + i * 16 + lr][lq * 8]);
#pragma unroll
    for (int i = 0; i < 4; ++i)
      bfr[i] = *reinterpret_cast<const bf16x8*>(&Bs[wc * 64 + i * 16 + lr][lq * 8]);
#pragma unroll
    for (int mi = 0; mi < 4; ++mi)
#pragma unroll
      for (int ni = 0; ni < 4; ++ni)
        acc[mi][ni] = __builtin_amdgcn_mfma_f32_16x16x32_bf16(af[mi], bfr[ni], acc[mi][ni], 0, 0, 0);
    __syncthreads();
  }

  // epilogue: D layout row=(lane>>4)*4+i, col=lane&15
#pragma unroll
  for (int mi = 0; mi < 4; ++mi) {
#pragma unroll
    for (int ni = 0; ni < 4; ++ni) {
      int col = bn0 + wc * 64 + ni * 16 + lr;
      float bv = (EPI >= 1) ? bias[col] : 0.0f;
#pragma unroll
      for (int i = 0; i < 4; ++i) {
        int row = bm0 + wr * 64 + mi * 16 + lq * 4 + i;
        float v = acc[mi][ni][i] + bv;
        if (EPI == 2) v = 0.5f * v * (1.0f + erff(v * 0.70710678118654752f));
        C[(size_t)row * N + col] = v;
      }
    }
  }
}

// ---------------- causal flash attention ----------------
// qkv: [B*L, 3072] rows; q at col 0, k at 1024, v at 2048 (+h*64)
// out: [B*L, 1024]
__global__ __launch_bounds__(256) void attn_k(const float* __restrict__ qkv,
                                              float* __restrict__ out) {
  const int qt = blockIdx.x;            // 64-row q tile
  const int b = blockIdx.y >> 4, h = blockIdx.y & 15;
  __shared__ __bf16 Ks[32][72];         // [key][d]  row stride 144B (16B aligned)
  __shared__ __bf16 Vt[64][40];         // [d][key]  transposed V
  __shared__ __bf16 Pl[4][16][40];      // per-wave P round-trip
  const int tid  = threadIdx.x;
  const int lane = tid & 63, wave = tid >> 6;
  const int lr = lane & 15, lq = lane >> 4;
  const int qbase = qt * 64 + wave * 16;
  const float scale = 0.125f;           // 1/sqrt(64)

  // Q fragments (scale folded in)
  bf16x8 aq[2];
  {
    const float* qp = qkv + (size_t)(b * L_SEQ + qbase + lr) * QKV_LD + h * HDIM;
#pragma unroll
    for (int kk = 0; kk < 2; ++kk) {
      float4 v0 = *reinterpret_cast<const float4*>(qp + kk * 32 + lq * 8);
      float4 v1 = *reinterpret_cast<const float4*>(qp + kk * 32 + lq * 8 + 4);
      aq[kk][0] = f2b(v0.x * scale); aq[kk][1] = f2b(v0.y * scale);
      aq[kk][2] = f2b(v0.z * scale); aq[kk][3] = f2b(v0.w * scale);
      aq[kk][4] = f2b(v1.x * scale); aq[kk][5] = f2b(v1.y * scale);
      aq[kk][6] = f2b(v1.z * scale); aq[kk][7] = f2b(v1.w * scale);
    }
  }

  f32x4 o[4] = {};
  float mrow[4], lsum[4];
#pragma unroll
  for (int i = 0; i < 4; ++i) { mrow[i] = -1e30f; lsum[i] = 0.0f; }

  const int tmax = 2 * qt + 1;
  for (int t = 0; t <= tmax; ++t) {
    const int k0 = t * 32;
    // cooperative stage of K (row-major) and V (transposed)
#pragma unroll
    for (int r = 0; r < 2; ++r) {
      int f = tid + 256 * r;
      int key = f >> 4, dq = f & 15;
      const float* kp = qkv + (size_t)(b * L_SEQ + k0 + key) * QKV_LD + DM + h * HDIM + dq * 4;
      float4 kv = *reinterpret_cast<const float4*>(kp);
      bf16x4 w; w[0] = f2b(kv.x); w[1] = f2b(kv.y); w[2] = f2b(kv.z); w[3] = f2b(kv.w);
      *reinterpret_cast<bf16x4*>(&Ks[key][dq * 4]) = w;
      const float* vp = qkv + (size_t)(b * L_SEQ + k0 + key) * QKV_LD + 2 * DM + h * HDIM + dq * 4;
      float4 vv = *reinterpret_cast<const float4*>(vp);
      Vt[dq * 4 + 0][key] = f2b(vv.x);
      Vt[dq * 4 + 1][key] = f2b(vv.y);
      Vt[dq * 4 + 2][key] = f2b(vv.z);
      Vt[dq * 4 + 3][key] = f2b(vv.w);
    }
    __syncthreads();

    if (k0 <= qbase) {                  // tile has live (unmasked) keys for this wave
      // S = Q K^T : two 16x16 D-frags (key blocks)
      f32x4 s[2] = {};
#pragma unroll
      for (int kb = 0; kb < 2; ++kb)
#pragma unroll
        for (int kk = 0; kk < 2; ++kk) {
          bf16x8 bk = *reinterpret_cast<const bf16x8*>(&Ks[kb * 16 + lr][kk * 32 + lq * 8]);
          s[kb] = __builtin_amdgcn_mfma_f32_16x16x32_bf16(aq[kk], bk, s[kb], 0, 0, 0);
        }
      // mask + online softmax (rows r = lq*4+i, cols = kb*16+lr)
#pragma unroll
      for (int i = 0; i < 4; ++i) {
        const int gq = qbase + lq * 4 + i;
#pragma unroll
        for (int kb = 0; kb < 2; ++kb) {
          int gk = k0 + kb * 16 + lr;
          if (gk > gq) s[kb][i] = -1e30f;
        }
        float tm = fmaxf(s[0][i], s[1][i]);
        tm = fmaxf(tm, __shfl_xor(tm, 1));
        tm = fmaxf(tm, __shfl_xor(tm, 2));
        tm = fmaxf(tm, __shfl_xor(tm, 4));
        tm = fmaxf(tm, __shfl_xor(tm, 8));
        float mn  = fmaxf(mrow[i], tm);
        float fac = __expf(mrow[i] - mn);
        mrow[i] = mn;
        float p0 = __expf(s[0][i] - mn);
        float p1 = __expf(s[1][i] - mn);
        s[0][i] = p0; s[1][i] = p1;
        float rs = p0 + p1;
        rs += __shfl_xor(rs, 1);
        rs += __shfl_xor(rs, 2);
        rs += __shfl_xor(rs, 4);
        rs += __shfl_xor(rs, 8);
        lsum[i] = lsum[i] * fac + rs;
#pragma unroll
        for (int ni = 0; ni < 4; ++ni) o[ni][i] *= fac;
      }
      // P (D-layout) -> LDS -> A-fragment (wave-private, no barrier needed)
#pragma unroll
      for (int i = 0; i < 4; ++i) {
        Pl[wave][lq * 4 + i][lr]      = f2b(s[0][i]);
        Pl[wave][lq * 4 + i][16 + lr] = f2b(s[1][i]);
      }
      bf16x8 pa = *reinterpret_cast<const bf16x8*>(&Pl[wave][lr][lq * 8]);
#pragma unroll
      for (int ni = 0; ni < 4; ++ni) {
        bf16x8 bv = *reinterpret_cast<const bf16x8*>(&Vt[ni * 16 + lr][lq * 8]);
        o[ni] = __builtin_amdgcn_mfma_f32_16x16x32_bf16(pa, bv, o[ni], 0, 0, 0);
      }
    }
    __syncthreads();
  }

#pragma unroll
  for (int i = 0; i < 4; ++i) {
    const int row = qbase + lq * 4 + i;
    const float inv = 1.0f / lsum[i];
#pragma unroll
    for (int ni = 0; ni < 4; ++ni)
      out[(size_t)(b * L_SEQ + row) * DM + h * HDIM + ni * 16 + lr] = o[ni][i] * inv;
  }
}

// ---------------- LayerNorm: Y = LN(X + R) * g + be ----------------
__global__ __launch_bounds__(256) void ln_k(const float* __restrict__ X,
                                            const float* __restrict__ R,
                                            const float* __restrict__ g,
                                            const float* __restrict__ be,
                                            float* __restrict__ Y) {
  const int row = blockIdx.x;
  const int tid = threadIdx.x;
  const int lane = tid & 63, wave = tid >> 6;
  float4 x4 = *reinterpret_cast<const float4*>(X + (size_t)row * DM + tid * 4);
  float4 r4 = *reinterpret_cast<const float4*>(R + (size_t)row * DM + tid * 4);
  float v0 = x4.x + r4.x, v1 = x4.y + r4.y, v2 = x4.z + r4.z, v3 = x4.w + r4.w;
  float s  = v0 + v1 + v2 + v3;
  float ss = v0 * v0 + v1 * v1 + v2 * v2 + v3 * v3;
#pragma unroll
  for (int off = 1; off < 64; off <<= 1) {
    s  += __shfl_xor(s, off);
    ss += __shfl_xor(ss, off);
  }
  __shared__ float red[8];
  if (lane == 0) { red[wave] = s; red[4 + wave] = ss; }
  __syncthreads();
  float S  = red[0] + red[1] + red[2] + red[3];
  float SS = red[4] + red[5] + red[6] + red[7];
  float mu  = S * (1.0f / DM);
  float var = SS * (1.0f / DM) - mu * mu;
  float rsd = rsqrtf(var + 1e-5f);
  float4 gv = *reinterpret_cast<const float4*>(g + tid * 4);
  float4 bv = *reinterpret_cast<const float4*>(be + tid * 4);
  float4 y;
  y.x = (v0 - mu) * rsd * gv.x + bv.x;
  y.y = (v1 - mu) * rsd * gv.y + bv.y;
  y.z = (v2 - mu) * rsd * gv.z + bv.z;
  y.w = (v3 - mu) * rsd * gv.w + bv.w;
  *reinterpret_cast<float4*>(Y + (size_t)row * DM + tid * 4) = y;
}

extern "C" void kernel_launch(void* const* d_in, const int* in_sizes, int n_in,
                              void* d_out, int out_size, void* d_ws, size_t ws_size,
                              hipStream_t stream) {
  const float* x     = (const float*)d_in[0];
  const float* w_qkv = (const float*)d_in[1];
  const float* w_out = (const float*)d_in[2];
  const float* w1    = (const float*)d_in[3];
  const float* b1    = (const float*)d_in[4];
  const float* w2    = (const float*)d_in[5];
  const float* b2    = (const float*)d_in[6];
  const float* g1    = (const float*)d_in[7];
  const float* be1   = (const float*)d_in[8];
  const float* g2    = (const float*)d_in[9];
  const float* be2   = (const float*)d_in[10];
  float* outp = (float*)d_out;
  float* ws   = (float*)d_ws;
  const int M = NB * L_SEQ;  // 4096

  // workspace layout (floats). peak = 16.78M floats = 67 MB
  float* qkv  = ws;                            // [0, 12.58M)
  float* attn = ws + (size_t)M * QKV_LD;       // [12.58M, 16.78M)
  float* ln1  = ws;                            // reuse qkv region [0, 4.19M)
  float* ffh  = ws + (size_t)M * DM;           // [4.19M, 12.58M)
  float* ffo  = ws + (size_t)M * QKV_LD;       // reuse attn region
  float* proj = outp;                          // d_out as scratch

  // 1. qkv = x @ w_qkv
  gemm_k<0><<<dim3(QKV_LD / 128, M / 128), 256, 0, stream>>>(x, w_qkv, nullptr, qkv, M, QKV_LD, DM);
  // 2. attention
  attn_k<<<dim3(L_SEQ / 64, NB * NHEAD), 256, 0, stream>>>(qkv, attn);
  // 3. proj = attn @ w_out  (into d_out scratch)
  gemm_k<0><<<dim3(DM / 128, M / 128), 256, 0, stream>>>(attn, w_out, nullptr, proj, M, DM, DM);
  // 4. ln1 = LN(x + proj)
  ln_k<<<M, 256, 0, stream>>>(x, proj, g1, be1, ln1);
  // 5. ffh = gelu(ln1 @ w1 + b1)
  gemm_k<2><<<dim3(2 * DM / 128, M / 128), 256, 0, stream>>>(ln1, w1, b1, ffh, M, 2 * DM, DM);
  // 6. ffo = ffh @ w2 + b2
  gemm_k<1><<<dim3(DM / 128, M / 128), 256, 0, stream>>>(ffh, w2, b2, ffo, M, DM, 2 * DM);
  // 7. out = LN(ln1 + ffo)
  ln_k<<<M, 256, 0, stream>>>(ln1, ffo, g2, be2, outp);
}

// Round 2
// 296.363 us; speedup vs baseline: 2.1919x; 2.1919x over previous
//
#include <hip/hip_runtime.h>
#include <hip/hip_bf16.h>
#include <math.h>

#define L_SEQ 2048
#define NB 2
#define DM 1024
#define NHEAD 16
#define HDIM 64
#define QKV_LD 3072
#define RL 0.18033688011112042f   // 0.125 * log2(e)

typedef __attribute__((ext_vector_type(8))) __bf16 bf16x8;
typedef __attribute__((ext_vector_type(4))) float f32x4;
typedef __attribute__((ext_vector_type(8))) unsigned short u16x8;

typedef __attribute__((address_space(3))) unsigned int lds_u32;
typedef const __attribute__((address_space(1))) unsigned int glob_u32;
#define GLD16(g, l) __builtin_amdgcn_global_load_lds((glob_u32*)(g), (lds_u32*)(l), 16, 0, 0)

// ---------------- weight transpose+convert: WT[n][k] = bf16(W[k][n]) ----------------
__global__ __launch_bounds__(256) void wt_k(const float* __restrict__ W,
                                            __hip_bfloat16* __restrict__ WT,
                                            int K, int N) {
  __shared__ float t[32][33];
  const int k0 = blockIdx.x * 32, n0 = blockIdx.y * 32;
  const int c = threadIdx.x & 31, r = threadIdx.x >> 5;   // 8 rows per pass
#pragma unroll
  for (int i = 0; i < 4; ++i)
    t[r + 8 * i][c] = W[(size_t)(k0 + r + 8 * i) * N + n0 + c];
  __syncthreads();
#pragma unroll
  for (int i = 0; i < 4; ++i)
    WT[(size_t)(n0 + r + 8 * i) * K + k0 + c] = __float2bfloat16(t[c][r + 8 * i]);
}

// ---------------- f32 -> bf16 convert ----------------
__global__ __launch_bounds__(256) void cvt_k(const float* __restrict__ X,
                                             __hip_bfloat16* __restrict__ Y) {
  const size_t base = ((size_t)blockIdx.x * 256 + threadIdx.x) * 8;
  float4 a = *reinterpret_cast<const float4*>(X + base);
  float4 b = *reinterpret_cast<const float4*>(X + base + 4);
  bf16x8 o;
  o[0] = (__bf16)a.x; o[1] = (__bf16)a.y; o[2] = (__bf16)a.z; o[3] = (__bf16)a.w;
  o[4] = (__bf16)b.x; o[5] = (__bf16)b.y; o[6] = (__bf16)b.z; o[7] = (__bf16)b.w;
  *reinterpret_cast<bf16x8*>(Y + base) = o;
}

// ---------------- GEMM (m97 structure): C = A[M,K] @ BT[N,K]^T ----------------
// EPI: 0 none, 1 +bias, 2 +bias+gelu.  OUTB: 1 -> bf16 out (Cb), 0 -> f32 out (Cf)
template<int EPI, int OUTB>
__global__ __launch_bounds__(256) void gemm2(const __hip_bfloat16* __restrict__ A,
                                             const __hip_bfloat16* __restrict__ BT,
                                             const float* __restrict__ bias,
                                             float* __restrict__ Cf,
                                             __hip_bfloat16* __restrict__ Cb,
                                             int M, int N, int K) {
  __shared__ __align__(16) __hip_bfloat16 As[128 * 32];
  __shared__ __align__(16) __hip_bfloat16 Bs[128 * 32];
  const int tid  = threadIdx.x;
  const int lane = tid & 63, wave = tid >> 6;
  const int wr = wave >> 1, wc = wave & 1;
  const int lr = lane & 15, lq = lane >> 4;
  const int bm0 = blockIdx.y * 128, bn0 = blockIdx.x * 128;
  f32x4 acc[4][4] = {};

  for (int k0 = 0; k0 < K; k0 += 32) {
#pragma unroll
    for (int j = 0; j < 2; ++j) {
      const int cbase = j * 256 + wave * 64;          // wave-uniform chunk base
      const int c = cbase + lane;
      const int row = c >> 2, kq = (c & 3) * 8;
      GLD16(A  + (size_t)(bm0 + row) * K + k0 + kq, (char*)As + cbase * 16);
      GLD16(BT + (size_t)(bn0 + row) * K + k0 + kq, (char*)Bs + cbase * 16);
    }
    __syncthreads();
    bf16x8 af[4], bfr[4];
#pragma unroll
    for (int i = 0; i < 4; ++i)
      af[i] = *reinterpret_cast<const bf16x8*>(As + (wr * 64 + i * 16 + lr) * 32 + lq * 8);
#pragma unroll
    for (int i = 0; i < 4; ++i)
      bfr[i] = *reinterpret_cast<const bf16x8*>(Bs + (wc * 64 + i * 16 + lr) * 32 + lq * 8);
#pragma unroll
    for (int mi = 0; mi < 4; ++mi)
#pragma unroll
      for (int ni = 0; ni < 4; ++ni)
        acc[mi][ni] = __builtin_amdgcn_mfma_f32_16x16x32_bf16(af[mi], bfr[ni], acc[mi][ni], 0, 0, 0);
    __syncthreads();
  }

#pragma unroll
  for (int mi = 0; mi < 4; ++mi) {
#pragma unroll
    for (int ni = 0; ni < 4; ++ni) {
      const int col = bn0 + wc * 64 + ni * 16 + lr;
      const float bv = (EPI >= 1) ? bias[col] : 0.0f;
#pragma unroll
      for (int j = 0; j < 4; ++j) {
        const int row = bm0 + wr * 64 + mi * 16 + lq * 4 + j;
        float v = acc[mi][ni][j] + bv;
        if (EPI == 2) v = 0.5f * v * (1.0f + erff(v * 0.70710678118654752f));
        if (OUTB) Cb[(size_t)row * N + col] = __float2bfloat16(v);
        else      Cf[(size_t)row * N + col] = v;
      }
    }
  }
}

// ---------------- causal flash attention (bf16 qkv in, bf16 out) ----------------
__global__ __launch_bounds__(256) void attn_k(const __hip_bfloat16* __restrict__ qkv,
                                              __hip_bfloat16* __restrict__ outb) {
  const int qt = 31 - blockIdx.y;               // heavy q-tiles dispatched first
  const int b = blockIdx.x >> 4, h = blockIdx.x & 15;
  __shared__ __align__(16) __hip_bfloat16 Ks[64 * 64];   // [key][d], row 128B, XOR swz (key&7)<<4
  __shared__ __align__(16) __hip_bfloat16 Vt[64 * 64];   // [d][key], row 128B, XOR swz x(d)<<4
  __shared__ __align__(16) __hip_bfloat16 Pl[4][16 * 64];// per-wave P, XOR swz (row&7)<<4
  const int tid  = threadIdx.x;
  const int lane = tid & 63, wave = tid >> 6;
  const int lr = lane & 15, lq = lane >> 4;
  const int qbase = qt * 64 + wave * 16;
  const size_t rowbase = (size_t)(b * L_SEQ) * QKV_LD;

  // Q fragments (A-frag: lane holds Q[qbase+lr][kk*32 + lq*8 + j])
  bf16x8 aq[2];
  {
    const __hip_bfloat16* qp = qkv + rowbase + (size_t)(qbase + lr) * QKV_LD + h * HDIM;
    aq[0] = *reinterpret_cast<const bf16x8*>(qp + lq * 8);
    aq[1] = *reinterpret_cast<const bf16x8*>(qp + 32 + lq * 8);
  }

  f32x4 o[4] = {};
  float mrow[4], lsum[4];
#pragma unroll
  for (int j = 0; j < 4; ++j) { mrow[j] = -1e30f; lsum[j] = 0.0f; }

  for (int t = 0; t <= qt; ++t) {
    const int k0 = t * 64;
    // ---- stage K (row-major, swizzled) ----
#pragma unroll
    for (int j = 0; j < 2; ++j) {
      const int c = tid + 256 * j;
      const int key = c >> 3, d8 = c & 7;
      bf16x8 kv = *reinterpret_cast<const bf16x8*>(
          qkv + rowbase + (size_t)(k0 + key) * QKV_LD + DM + h * HDIM + d8 * 8);
      const int bo = (key * 128 + d8 * 16) ^ ((key & 7) << 4);
      *reinterpret_cast<bf16x8*>((char*)Ks + bo) = kv;
    }
    // ---- stage V transposed (paired u32 writes, swizzled) ----
    {
      const int kp = tid >> 3, d8 = tid & 7;   // key pair, d-chunk
      const __hip_bfloat16* vp = qkv + rowbase + (size_t)(k0 + 2 * kp) * QKV_LD + 2 * DM + h * HDIM + d8 * 8;
      u16x8 v0 = *reinterpret_cast<const u16x8*>(vp);
      u16x8 v1 = *reinterpret_cast<const u16x8*>(vp + QKV_LD);
#pragma unroll
      for (int i = 0; i < 8; ++i) {
        const int d = d8 * 8 + i;
        const unsigned int pk = (unsigned int)v0[i] | ((unsigned int)v1[i] << 16);
        const int x = ((d >> 3) ^ ((d & 1) << 2)) & 7;
        const int bo = (d * 128 + kp * 4) ^ (x << 4);
        *reinterpret_cast<unsigned int*>((char*)Vt + bo) = pk;
      }
    }
    __syncthreads();

    // live kb frags for this wave (only last live kb needs masking)
    int nkb = ((qbase - k0 + 15) >> 4) + 1;
    if (nkb > 4) nkb = 4;
    const int nkc = (nkb + 1) >> 1;

    f32x4 s[4];
#pragma unroll
    for (int kb = 0; kb < 4; ++kb) {
      if (kb < nkb) {
        f32x4 z = {};
#pragma unroll
        for (int kk = 0; kk < 2; ++kk) {
          const int bo = ((kb * 16 + lr) * 128 + kk * 64 + lq * 16) ^ ((lr & 7) << 4);
          bf16x8 bk = *reinterpret_cast<const bf16x8*>((char*)Ks + bo);
          z = __builtin_amdgcn_mfma_f32_16x16x32_bf16(aq[kk], bk, z, 0, 0, 0);
        }
        s[kb] = z;
      }
    }
    // mask last live kb
    {
      const int kb = nkb - 1;
      const int gk = k0 + kb * 16 + lr;
#pragma unroll
      for (int j = 0; j < 4; ++j)
        if (gk > qbase + lq * 4 + j) s[kb][j] = -1e30f;
    }
    // online softmax per row (rows = lq*4+j, cols across 16 lanes of lr)
#pragma unroll
    for (int j = 0; j < 4; ++j) {
      float tm = -1e30f;
#pragma unroll
      for (int kb = 0; kb < 4; ++kb)
        if (kb < nkb) tm = fmaxf(tm, s[kb][j]);
      tm = fmaxf(tm, __shfl_xor(tm, 1));
      tm = fmaxf(tm, __shfl_xor(tm, 2));
      tm = fmaxf(tm, __shfl_xor(tm, 4));
      tm = fmaxf(tm, __shfl_xor(tm, 8));
      const float mn = fmaxf(mrow[j], tm);
      const float fac = exp2f((mrow[j] - mn) * RL);
      mrow[j] = mn;
      float rs = 0.0f;
#pragma unroll
      for (int kb = 0; kb < 4; ++kb) {
        if (kb < nkb) { s[kb][j] = exp2f((s[kb][j] - mn) * RL); rs += s[kb][j]; }
        else s[kb][j] = 0.0f;
      }
      rs += __shfl_xor(rs, 1);
      rs += __shfl_xor(rs, 2);
      rs += __shfl_xor(rs, 4);
      rs += __shfl_xor(rs, 8);
      lsum[j] = lsum[j] * fac + rs;
#pragma unroll
      for (int ni = 0; ni < 4; ++ni) o[ni][j] *= fac;
    }
    // P (D-layout) -> wave-private LDS (swizzled) -> A-fragments
    {
      char* Pb = (char*)&Pl[wave][0];
#pragma unroll
      for (int j = 0; j < 4; ++j) {
        const int row = lq * 4 + j;
        const int rx = (row & 7) << 4;
#pragma unroll
        for (int kb = 0; kb < 4; ++kb) {
          const int bo = (row * 128 + (kb * 16 + lr) * 2) ^ rx;
          *reinterpret_cast<__hip_bfloat16*>(Pb + bo) = __float2bfloat16(s[kb][j]);
        }
      }
      for (int kc = 0; kc < nkc; ++kc) {
        const int pb = (lr * 128 + kc * 64 + lq * 16) ^ ((lr & 7) << 4);
        bf16x8 pa = *reinterpret_cast<const bf16x8*>(Pb + pb);
#pragma unroll
        for (int ni = 0; ni < 4; ++ni) {
          const int row = ni * 16 + lr;
          const int x = ((row >> 3) ^ ((row & 1) << 2)) & 7;
          const int bo = (row * 128 + kc * 64 + lq * 16) ^ (x << 4);
          bf16x8 bv = *reinterpret_cast<const bf16x8*>((char*)Vt + bo);
          o[ni] = __builtin_amdgcn_mfma_f32_16x16x32_bf16(pa, bv, o[ni], 0, 0, 0);
        }
      }
    }
    __syncthreads();
  }

#pragma unroll
  for (int j = 0; j < 4; ++j) {
    const int row = qbase + lq * 4 + j;
    const float inv = 1.0f / lsum[j];
#pragma unroll
    for (int ni = 0; ni < 4; ++ni)
      outb[(size_t)(b * L_SEQ + row) * DM + h * HDIM + ni * 16 + lr] = __float2bfloat16(o[ni][j] * inv);
  }
}

// ---------------- LayerNorm: Y = LN(X + R) * g + be (optional bf16 copy) ----------------
template<int WB>
__global__ __launch_bounds__(256) void ln_k(const float* __restrict__ X,
                                            const float* __restrict__ R,
                                            const float* __restrict__ g,
                                            const float* __restrict__ be,
                                            float* __restrict__ Y,
                                            __hip_bfloat16* __restrict__ Yb) {
  const int row = blockIdx.x;
  const int tid = threadIdx.x;
  const int lane = tid & 63, wave = tid >> 6;
  float4 x4 = *reinterpret_cast<const float4*>(X + (size_t)row * DM + tid * 4);
  float4 r4 = *reinterpret_cast<const float4*>(R + (size_t)row * DM + tid * 4);
  float v0 = x4.x + r4.x, v1 = x4.y + r4.y, v2 = x4.z + r4.z, v3 = x4.w + r4.w;
  float s  = v0 + v1 + v2 + v3;
  float ss = v0 * v0 + v1 * v1 + v2 * v2 + v3 * v3;
#pragma unroll
  for (int off = 1; off < 64; off <<= 1) {
    s  += __shfl_xor(s, off);
    ss += __shfl_xor(ss, off);
  }
  __shared__ float red[8];
  if (lane == 0) { red[wave] = s; red[4 + wave] = ss; }
  __syncthreads();
  float S  = red[0] + red[1] + red[2] + red[3];
  float SS = red[4] + red[5] + red[6] + red[7];
  float mu  = S * (1.0f / DM);
  float var = SS * (1.0f / DM) - mu * mu;
  float rsd = rsqrtf(var + 1e-5f);
  float4 gv = *reinterpret_cast<const float4*>(g + tid * 4);
  float4 bv = *reinterpret_cast<const float4*>(be + tid * 4);
  float4 y;
  y.x = (v0 - mu) * rsd * gv.x + bv.x;
  y.y = (v1 - mu) * rsd * gv.y + bv.y;
  y.z = (v2 - mu) * rsd * gv.z + bv.z;
  y.w = (v3 - mu) * rsd * gv.w + bv.w;
  *reinterpret_cast<float4*>(Y + (size_t)row * DM + tid * 4) = y;
  if (WB) {
    typedef __attribute__((ext_vector_type(4))) __bf16 bf16x4;
    bf16x4 yb;
    yb[0] = (__bf16)y.x; yb[1] = (__bf16)y.y; yb[2] = (__bf16)y.z; yb[3] = (__bf16)y.w;
    *reinterpret_cast<bf16x4*>(Yb + (size_t)row * DM + tid * 4) = yb;
  }
}

extern "C" void kernel_launch(void* const* d_in, const int* in_sizes, int n_in,
                              void* d_out, int out_size, void* d_ws, size_t ws_size,
                              hipStream_t stream) {
  const float* x     = (const float*)d_in[0];
  const float* w_qkv = (const float*)d_in[1];
  const float* w_out = (const float*)d_in[2];
  const float* w1    = (const float*)d_in[3];
  const float* b1    = (const float*)d_in[4];
  const float* w2    = (const float*)d_in[5];
  const float* b2    = (const float*)d_in[6];
  const float* g1    = (const float*)d_in[7];
  const float* be1   = (const float*)d_in[8];
  const float* g2    = (const float*)d_in[9];
  const float* be2   = (const float*)d_in[10];
  float* outp = (float*)d_out;
  char* base  = (char*)d_ws;
  const int M = NB * L_SEQ;                 // 4096

  // workspace layout (byte offsets, 64 MiB total; lifetimes traced)
  __hip_bfloat16* w2T  = (__hip_bfloat16*)(base + 0);          // [1024][2048]
  __hip_bfloat16* woT  = (__hip_bfloat16*)(base + 4194304);    // [1024][1024]
  __hip_bfloat16* w1T  = (__hip_bfloat16*)(base + 6291456);    // [2048][1024]
  __hip_bfloat16* wqT  = (__hip_bfloat16*)(base + 10485760);   // [3072][1024]
  __hip_bfloat16* xb   = (__hip_bfloat16*)(base + 16777216);   // [4096][1024]
  __hip_bfloat16* attnb= xb;                                   // reuse after qkv GEMM
  __hip_bfloat16* qkvb = (__hip_bfloat16*)(base + 25165824);   // [4096][3072]
  __hip_bfloat16* ffh  = (__hip_bfloat16*)(base + 25165824);   // [4096][2048] (qkvb dead)
  __hip_bfloat16* ln1b = (__hip_bfloat16*)(base + 41943040);   // [4096][1024] (qkvb dead)
  float*          ffo  = (float*)(base + 8388608);             // [4096][1024] f32 (dead wts+xb)
  float*          ln1f = (float*)(base + 50331648);            // [4096][1024] f32
  float*          proj = outp;                                 // d_out as scratch

  // pre-passes: weight transpose+convert, x convert
  wt_k<<<dim3(32, 96), 256, 0, stream>>>(w_qkv, wqT, 1024, 3072);
  wt_k<<<dim3(32, 32), 256, 0, stream>>>(w_out, woT, 1024, 1024);
  wt_k<<<dim3(32, 64), 256, 0, stream>>>(w1,    w1T, 1024, 2048);
  wt_k<<<dim3(64, 32), 256, 0, stream>>>(w2,    w2T, 2048, 1024);
  cvt_k<<<2048, 256, 0, stream>>>(x, xb);

  // 1. qkv = x @ w_qkv        (bf16 out)
  gemm2<0, 1><<<dim3(24, 32), 256, 0, stream>>>(xb, wqT, nullptr, nullptr, qkvb, M, QKV_LD, DM);
  // 2. attention              (bf16 out)
  attn_k<<<dim3(32, 32), 256, 0, stream>>>(qkvb, attnb);
  // 3. proj = attn @ w_out    (f32 out into d_out scratch)
  gemm2<0, 0><<<dim3(8, 32), 256, 0, stream>>>(attnb, woT, nullptr, proj, nullptr, M, DM, DM);
  // 4. ln1 = LN(x + proj)     (f32 + bf16)
  ln_k<1><<<M, 256, 0, stream>>>(x, proj, g1, be1, ln1f, ln1b);
  // 5. ffh = gelu(ln1 @ w1 + b1)  (bf16 out)
  gemm2<2, 1><<<dim3(16, 32), 256, 0, stream>>>(ln1b, w1T, b1, nullptr, ffh, M, 2 * DM, DM);
  // 6. ffo = ffh @ w2 + b2    (f32 out)
  gemm2<1, 0><<<dim3(8, 32), 256, 0, stream>>>(ffh, w2T, b2, ffo, nullptr, M, DM, 2 * DM);
  // 7. out = LN(ln1 + ffo)
  ln_k<0><<<M, 256, 0, stream>>>(ln1f, ffo, g2, be2, outp, nullptr);
}

// Round 3
// 249.418 us; speedup vs baseline: 2.6045x; 1.1882x over previous
//
#include <hip/hip_runtime.h>
#include <hip/hip_bf16.h>
#include <math.h>

#define L_SEQ 2048
#define NB 2
#define DM 1024
#define NHEAD 16
#define HDIM 64
#define QKV_LD 3072
#define RL 0.18033688011112042f   // 0.125 * log2(e)

typedef __attribute__((ext_vector_type(8))) __bf16 bf16x8;
typedef __attribute__((ext_vector_type(4))) __bf16 bf16x4;
typedef __attribute__((ext_vector_type(4))) float f32x4;
typedef __attribute__((ext_vector_type(16))) float f32x16;
typedef __attribute__((ext_vector_type(8))) unsigned short u16x8;
typedef __attribute__((ext_vector_type(4))) unsigned int u32x4;

typedef __attribute__((address_space(3))) unsigned int lds_u32;
typedef const __attribute__((address_space(1))) unsigned int glob_u32;
#define GLD16(g, l) __builtin_amdgcn_global_load_lds((glob_u32*)(g), (lds_u32*)(l), 16, 0, 0)

__device__ __forceinline__ unsigned pack2(float a, float b) {
  unsigned short ua = __builtin_bit_cast(unsigned short, (__bf16)a);
  unsigned short ub = __builtin_bit_cast(unsigned short, (__bf16)b);
  return (unsigned)ua | ((unsigned)ub << 16);
}

// ---------------- weight transpose+convert: WT[n][k] = bf16(W[k][n]) ----------------
__global__ __launch_bounds__(256) void wt_k(const float* __restrict__ W,
                                            __hip_bfloat16* __restrict__ WT,
                                            int K, int N) {
  __shared__ float t[32][33];
  const int k0 = blockIdx.x * 32, n0 = blockIdx.y * 32;
  const int c = threadIdx.x & 31, r = threadIdx.x >> 5;
#pragma unroll
  for (int i = 0; i < 4; ++i)
    t[r + 8 * i][c] = W[(size_t)(k0 + r + 8 * i) * N + n0 + c];
  __syncthreads();
#pragma unroll
  for (int i = 0; i < 4; ++i)
    WT[(size_t)(n0 + r + 8 * i) * K + k0 + c] = __float2bfloat16(t[c][r + 8 * i]);
}

// ---------------- f32 -> bf16 convert ----------------
__global__ __launch_bounds__(256) void cvt_k(const float* __restrict__ X,
                                             __hip_bfloat16* __restrict__ Y) {
  const size_t base = ((size_t)blockIdx.x * 256 + threadIdx.x) * 8;
  float4 a = *reinterpret_cast<const float4*>(X + base);
  float4 b = *reinterpret_cast<const float4*>(X + base + 4);
  bf16x8 o;
  o[0] = (__bf16)a.x; o[1] = (__bf16)a.y; o[2] = (__bf16)a.z; o[3] = (__bf16)a.w;
  o[4] = (__bf16)b.x; o[5] = (__bf16)b.y; o[6] = (__bf16)b.z; o[7] = (__bf16)b.w;
  *reinterpret_cast<bf16x8*>(Y + base) = o;
}

// ---------------- GEMM (m97 structure): C = A[M,K] @ BT[N,K]^T ----------------
template<int EPI, int OUTB>
__global__ __launch_bounds__(256) void gemm2(const __hip_bfloat16* __restrict__ A,
                                             const __hip_bfloat16* __restrict__ BT,
                                             const float* __restrict__ bias,
                                             float* __restrict__ Cf,
                                             __hip_bfloat16* __restrict__ Cb,
                                             int M, int N, int K) {
  __shared__ __align__(16) __hip_bfloat16 As[128 * 32];
  __shared__ __align__(16) __hip_bfloat16 Bs[128 * 32];
  const int tid  = threadIdx.x;
  const int lane = tid & 63, wave = tid >> 6;
  const int wr = wave >> 1, wc = wave & 1;
  const int lr = lane & 15, lq = lane >> 4;
  const int bm0 = blockIdx.y * 128, bn0 = blockIdx.x * 128;
  f32x4 acc[4][4] = {};

  for (int k0 = 0; k0 < K; k0 += 32) {
#pragma unroll
    for (int j = 0; j < 2; ++j) {
      const int cbase = j * 256 + wave * 64;
      const int c = cbase + lane;
      const int row = c >> 2, kq = (c & 3) * 8;
      GLD16(A  + (size_t)(bm0 + row) * K + k0 + kq, (char*)As + cbase * 16);
      GLD16(BT + (size_t)(bn0 + row) * K + k0 + kq, (char*)Bs + cbase * 16);
    }
    __syncthreads();
    bf16x8 af[4], bfr[4];
#pragma unroll
    for (int i = 0; i < 4; ++i)
      af[i] = *reinterpret_cast<const bf16x8*>(As + (wr * 64 + i * 16 + lr) * 32 + lq * 8);
#pragma unroll
    for (int i = 0; i < 4; ++i)
      bfr[i] = *reinterpret_cast<const bf16x8*>(Bs + (wc * 64 + i * 16 + lr) * 32 + lq * 8);
#pragma unroll
    for (int mi = 0; mi < 4; ++mi)
#pragma unroll
      for (int ni = 0; ni < 4; ++ni)
        acc[mi][ni] = __builtin_amdgcn_mfma_f32_16x16x32_bf16(af[mi], bfr[ni], acc[mi][ni], 0, 0, 0);
    __syncthreads();
  }

#pragma unroll
  for (int mi = 0; mi < 4; ++mi) {
#pragma unroll
    for (int ni = 0; ni < 4; ++ni) {
      const int col = bn0 + wc * 64 + ni * 16 + lr;
      const float bv = (EPI >= 1) ? bias[col] : 0.0f;
#pragma unroll
      for (int j = 0; j < 4; ++j) {
        const int row = bm0 + wr * 64 + mi * 16 + lq * 4 + j;
        float v = acc[mi][ni][j] + bv;
        if (EPI == 2) v = 0.5f * v * (1.0f + erff(v * 0.70710678118654752f));
        if (OUTB) Cb[(size_t)row * N + col] = __float2bfloat16(v);
        else      Cf[(size_t)row * N + col] = v;
      }
    }
  }
}

// ---------------- causal flash attention v2: swapped-operand 32x32 MFMA ----------------
// Per wave: 32 q-rows; S^T = K @ Q^T so each lane owns one q-row (keys split
// across lane^32). Softmax in-register; P redistributed via packed shfl; PV as
// O^T = V^T @ P^T so rescale factors are lane-local.
#define QK_BLOCK(sv, rowoff)                                                       \
  _Pragma("unroll")                                                                \
  for (int ci = 0; ci < 4; ++ci) {                                                 \
    const int so = (((2 * ci + hi) ^ (lq32 & 7)) << 4);                            \
    bf16x8 ka = *reinterpret_cast<const bf16x8*>(Kc + ((rowoff) + lq32) * 128 + so);\
    sv = __builtin_amdgcn_mfma_f32_32x32x16_bf16(ka, qf[ci], sv, 0, 0, 0);         \
  }

#define DIAG_MASK(sv)                                                              \
  _Pragma("unroll")                                                                \
  for (int r = 0; r < 16; ++r) {                                                   \
    const int kl = (r & 3) + 8 * (r >> 2) + 4 * hi;                                \
    if (kl > lq32) sv[r] = -1e30f;                                                 \
  }

#define EXP_SUM(sv)                                                                \
  _Pragma("unroll")                                                                \
  for (int r = 0; r < 16; ++r) {                                                   \
    sv[r] = __builtin_amdgcn_exp2f(fmaf(sv[r], RL, mneg));                         \
    rs += sv[r];                                                                   \
  }

#define PV_HALF(wl0, wl1, wh0, wh1, ksg)                                           \
  {                                                                                \
    unsigned t0_ = hi ? (wl0) : (wh0);                                             \
    unsigned t1_ = hi ? (wl1) : (wh1);                                             \
    t0_ = (unsigned)__shfl_xor((int)t0_, 32);                                      \
    t1_ = (unsigned)__shfl_xor((int)t1_, 32);                                      \
    u32x4 fw;                                                                      \
    fw[0] = hi ? t0_ : (wl0);  fw[1] = hi ? t1_ : (wl1);                           \
    fw[2] = hi ? (wh0) : t0_;  fw[3] = hi ? (wh1) : t1_;                           \
    bf16x8 pf = __builtin_bit_cast(bf16x8, fw);                                    \
    const int so0 = (((2 * (ksg) + hi) ^ xs0) << 4);                               \
    bf16x8 va = *reinterpret_cast<const bf16x8*>(Vc + lq32 * 128 + so0);           \
    o0 = __builtin_amdgcn_mfma_f32_32x32x16_bf16(va, pf, o0, 0, 0, 0);             \
    const int so1 = (((2 * (ksg) + hi) ^ xs1) << 4);                               \
    bf16x8 vb = *reinterpret_cast<const bf16x8*>(Vc + (32 + lq32) * 128 + so1);    \
    o1 = __builtin_amdgcn_mfma_f32_32x32x16_bf16(vb, pf, o1, 0, 0, 0);             \
  }

#define PV_BLOCK(sv, kb)                                                           \
  {                                                                                \
    unsigned w0_ = pack2(sv[0], sv[1]),   w1_ = pack2(sv[2], sv[3]);               \
    unsigned w2_ = pack2(sv[4], sv[5]),   w3_ = pack2(sv[6], sv[7]);               \
    unsigned w4_ = pack2(sv[8], sv[9]),   w5_ = pack2(sv[10], sv[11]);             \
    unsigned w6_ = pack2(sv[12], sv[13]), w7_ = pack2(sv[14], sv[15]);             \
    PV_HALF(w0_, w1_, w2_, w3_, 2 * (kb))                                          \
    PV_HALF(w4_, w5_, w6_, w7_, 2 * (kb) + 1)                                      \
  }

__global__ __launch_bounds__(256) void attn_k(const __hip_bfloat16* __restrict__ qkv,
                                              __hip_bfloat16* __restrict__ outb) {
  const int qt = 15 - blockIdx.y;               // heavy q-tiles first
  const int b = blockIdx.x >> 4, h = blockIdx.x & 15;
  __shared__ __align__(16) __hip_bfloat16 Ks[64 * 64];   // [key][d], 128B rows, chunk^=(key&7)
  __shared__ __align__(16) __hip_bfloat16 Vt[64 * 64];   // [d][key], 128B rows, chunk^=x(d)
  char* const Kc = (char*)Ks;
  char* const Vc = (char*)Vt;
  const int tid  = threadIdx.x;
  const int lane = tid & 63, wave = tid >> 6;
  const int lq32 = lane & 31, hi = lane >> 5;
  const int qb = qt * 128 + wave * 32;
  const int qg = qb + lq32;
  const size_t rowbase = (size_t)(b * L_SEQ) * QKV_LD;
  const int xs0 = ((lq32 >> 3) ^ ((lq32 & 1) << 2)) & 7;
  const int xs1 = (((32 + lq32) >> 3) ^ ((lq32 & 1) << 2)) & 7;

  // Q B-frags: lane holds Q[qg][16c + 8hi + j]
  bf16x8 qf[4];
  {
    const __hip_bfloat16* qp = qkv + rowbase + (size_t)qg * QKV_LD + h * HDIM + 8 * hi;
#pragma unroll
    for (int c = 0; c < 4; ++c)
      qf[c] = *reinterpret_cast<const bf16x8*>(qp + 16 * c);
  }

  f32x16 o0 = {}, o1 = {};
  float m = -1e30f, lsum = 0.0f;

  const int ntiles = 2 * qt + 2;
  for (int t = 0; t < ntiles; ++t) {
    const int k0 = t * 64;
    // ---- V loads first (independent of K staging) ----
    const int kp = tid >> 3, d8 = tid & 7;
    const __hip_bfloat16* vp = qkv + rowbase + (size_t)(k0 + 2 * kp) * QKV_LD + 2 * DM + h * HDIM + d8 * 8;
    u16x8 v0 = *reinterpret_cast<const u16x8*>(vp);
    u16x8 v1 = *reinterpret_cast<const u16x8*>(vp + QKV_LD);
    // ---- K -> LDS direct, pre-swizzled global source (rule 21) ----
#pragma unroll
    for (int j = 0; j < 2; ++j) {
      const int cbase = j * 256 + wave * 64;
      const int c = cbase + lane;
      const int key = c >> 3, slot = c & 7;
      const int gchunk = slot ^ (key & 7);
      GLD16(qkv + rowbase + (size_t)(k0 + key) * QKV_LD + DM + h * HDIM + gchunk * 8,
            Kc + cbase * 16);
    }
    // ---- V^T staging (paired u32 writes, swizzled) ----
#pragma unroll
    for (int i = 0; i < 8; ++i) {
      const int d = d8 * 8 + i;
      const unsigned pk = (unsigned)v0[i] | ((unsigned)v1[i] << 16);
      const int x = ((d >> 3) ^ ((d & 1) << 2)) & 7;
      const int bo = (d * 128 + kp * 4) ^ (x << 4);
      *reinterpret_cast<unsigned*>(Vc + bo) = pk;
    }
    __syncthreads();

    if (k0 <= qb + 31) {                       // wave has live keys in this tile
      float rs = 0.0f;
      const bool has1 = (k0 < qb);
      if (has1) {
        f32x16 s0 = {}, s1 = {};
        QK_BLOCK(s0, 0)
        QK_BLOCK(s1, 32)
        if (k0 + 32 == qb) { DIAG_MASK(s1) }
        float tm = s0[0];
#pragma unroll
        for (int r = 1; r < 16; ++r) tm = fmaxf(tm, s0[r]);
#pragma unroll
        for (int r = 0; r < 16; ++r) tm = fmaxf(tm, s1[r]);
        tm = fmaxf(tm, __shfl_xor(tm, 32));
        if (!__all(tm <= m)) {
          const float mn = fmaxf(m, tm);
          const float fac = __builtin_amdgcn_exp2f((m - mn) * RL);
          m = mn; lsum *= fac; o0 *= fac; o1 *= fac;
        }
        const float mneg = -m * RL;
        EXP_SUM(s0)
        EXP_SUM(s1)
        rs += __shfl_xor(rs, 32);
        lsum += rs;
        PV_BLOCK(s0, 0)
        PV_BLOCK(s1, 1)
      } else {                                  // k0 == qb: single diagonal block
        f32x16 s0 = {};
        QK_BLOCK(s0, 0)
        DIAG_MASK(s0)
        float tm = s0[0];
#pragma unroll
        for (int r = 1; r < 16; ++r) tm = fmaxf(tm, s0[r]);
        tm = fmaxf(tm, __shfl_xor(tm, 32));
        if (!__all(tm <= m)) {
          const float mn = fmaxf(m, tm);
          const float fac = __builtin_amdgcn_exp2f((m - mn) * RL);
          m = mn; lsum *= fac; o0 *= fac; o1 *= fac;
        }
        const float mneg = -m * RL;
        EXP_SUM(s0)
        rs += __shfl_xor(rs, 32);
        lsum += rs;
        PV_BLOCK(s0, 0)
      }
    }
    __syncthreads();
  }

  // epilogue: O^T regs -> out; lane owns col q=qg, rows d = (r&3)+8(r>>2)+4hi (+32 for o1)
  const float inv = 1.0f / lsum;
  __hip_bfloat16* orow = outb + (size_t)(b * L_SEQ + qg) * DM + h * HDIM + 4 * hi;
#pragma unroll
  for (int rg = 0; rg < 4; ++rg) {
    bf16x4 ov;
#pragma unroll
    for (int i = 0; i < 4; ++i) ov[i] = (__bf16)(o0[4 * rg + i] * inv);
    *reinterpret_cast<bf16x4*>(orow + 8 * rg) = ov;
#pragma unroll
    for (int i = 0; i < 4; ++i) ov[i] = (__bf16)(o1[4 * rg + i] * inv);
    *reinterpret_cast<bf16x4*>(orow + 32 + 8 * rg) = ov;
  }
}

// ---------------- LayerNorm: Y = LN(X + R) * g + be (optional bf16 copy) ----------------
template<int WB>
__global__ __launch_bounds__(256) void ln_k(const float* __restrict__ X,
                                            const float* __restrict__ R,
                                            const float* __restrict__ g,
                                            const float* __restrict__ be,
                                            float* __restrict__ Y,
                                            __hip_bfloat16* __restrict__ Yb) {
  const int row = blockIdx.x;
  const int tid = threadIdx.x;
  const int lane = tid & 63, wave = tid >> 6;
  float4 x4 = *reinterpret_cast<const float4*>(X + (size_t)row * DM + tid * 4);
  float4 r4 = *reinterpret_cast<const float4*>(R + (size_t)row * DM + tid * 4);
  float v0 = x4.x + r4.x, v1 = x4.y + r4.y, v2 = x4.z + r4.z, v3 = x4.w + r4.w;
  float s  = v0 + v1 + v2 + v3;
  float ss = v0 * v0 + v1 * v1 + v2 * v2 + v3 * v3;
#pragma unroll
  for (int off = 1; off < 64; off <<= 1) {
    s  += __shfl_xor(s, off);
    ss += __shfl_xor(ss, off);
  }
  __shared__ float red[8];
  if (lane == 0) { red[wave] = s; red[4 + wave] = ss; }
  __syncthreads();
  float S  = red[0] + red[1] + red[2] + red[3];
  float SS = red[4] + red[5] + red[6] + red[7];
  float mu  = S * (1.0f / DM);
  float var = SS * (1.0f / DM) - mu * mu;
  float rsd = rsqrtf(var + 1e-5f);
  float4 gv = *reinterpret_cast<const float4*>(g + tid * 4);
  float4 bv = *reinterpret_cast<const float4*>(be + tid * 4);
  float4 y;
  y.x = (v0 - mu) * rsd * gv.x + bv.x;
  y.y = (v1 - mu) * rsd * gv.y + bv.y;
  y.z = (v2 - mu) * rsd * gv.z + bv.z;
  y.w = (v3 - mu) * rsd * gv.w + bv.w;
  *reinterpret_cast<float4*>(Y + (size_t)row * DM + tid * 4) = y;
  if (WB) {
    bf16x4 yb;
    yb[0] = (__bf16)y.x; yb[1] = (__bf16)y.y; yb[2] = (__bf16)y.z; yb[3] = (__bf16)y.w;
    *reinterpret_cast<bf16x4*>(Yb + (size_t)row * DM + tid * 4) = yb;
  }
}

extern "C" void kernel_launch(void* const* d_in, const int* in_sizes, int n_in,
                              void* d_out, int out_size, void* d_ws, size_t ws_size,
                              hipStream_t stream) {
  const float* x     = (const float*)d_in[0];
  const float* w_qkv = (const float*)d_in[1];
  const float* w_out = (const float*)d_in[2];
  const float* w1    = (const float*)d_in[3];
  const float* b1    = (const float*)d_in[4];
  const float* w2    = (const float*)d_in[5];
  const float* b2    = (const float*)d_in[6];
  const float* g1    = (const float*)d_in[7];
  const float* be1   = (const float*)d_in[8];
  const float* g2    = (const float*)d_in[9];
  const float* be2   = (const float*)d_in[10];
  float* outp = (float*)d_out;
  char* base  = (char*)d_ws;
  const int M = NB * L_SEQ;                 // 4096

  __hip_bfloat16* w2T  = (__hip_bfloat16*)(base + 0);          // [1024][2048]
  __hip_bfloat16* woT  = (__hip_bfloat16*)(base + 4194304);    // [1024][1024]
  __hip_bfloat16* w1T  = (__hip_bfloat16*)(base + 6291456);    // [2048][1024]
  __hip_bfloat16* wqT  = (__hip_bfloat16*)(base + 10485760);   // [3072][1024]
  __hip_bfloat16* xb   = (__hip_bfloat16*)(base + 16777216);   // [4096][1024]
  __hip_bfloat16* attnb= xb;                                   // reuse after qkv GEMM
  __hip_bfloat16* qkvb = (__hip_bfloat16*)(base + 25165824);   // [4096][3072]
  __hip_bfloat16* ffh  = (__hip_bfloat16*)(base + 25165824);   // [4096][2048] (qkvb dead)
  __hip_bfloat16* ln1b = (__hip_bfloat16*)(base + 41943040);   // [4096][1024] (qkvb dead)
  float*          ffo  = (float*)(base + 8388608);             // [4096][1024] f32
  float*          ln1f = (float*)(base + 50331648);            // [4096][1024] f32
  float*          proj = outp;                                 // d_out as scratch

  wt_k<<<dim3(32, 96), 256, 0, stream>>>(w_qkv, wqT, 1024, 3072);
  wt_k<<<dim3(32, 32), 256, 0, stream>>>(w_out, woT, 1024, 1024);
  wt_k<<<dim3(32, 64), 256, 0, stream>>>(w1,    w1T, 1024, 2048);
  wt_k<<<dim3(64, 32), 256, 0, stream>>>(w2,    w2T, 2048, 1024);
  cvt_k<<<2048, 256, 0, stream>>>(x, xb);

  gemm2<0, 1><<<dim3(24, 32), 256, 0, stream>>>(xb, wqT, nullptr, nullptr, qkvb, M, QKV_LD, DM);
  attn_k<<<dim3(32, 16), 256, 0, stream>>>(qkvb, attnb);
  gemm2<0, 0><<<dim3(8, 32), 256, 0, stream>>>(attnb, woT, nullptr, proj, nullptr, M, DM, DM);
  ln_k<1><<<M, 256, 0, stream>>>(x, proj, g1, be1, ln1f, ln1b);
  gemm2<2, 1><<<dim3(16, 32), 256, 0, stream>>>(ln1b, w1T, b1, nullptr, ffh, M, 2 * DM, DM);
  gemm2<1, 0><<<dim3(8, 32), 256, 0, stream>>>(ffh, w2T, b2, ffo, nullptr, M, DM, 2 * DM);
  ln_k<0><<<M, 256, 0, stream>>>(ln1f, ffo, g2, be2, outp, nullptr);
}

// Round 4
// 242.030 us; speedup vs baseline: 2.6840x; 1.0305x over previous
//
#include <hip/hip_runtime.h>
#include <hip/hip_bf16.h>
#include <math.h>

#define L_SEQ 2048
#define NB 2
#define DM 1024
#define NHEAD 16
#define HDIM 64
#define QKV_LD 3072
#define RL 0.18033688011112042f   // 0.125 * log2(e)

typedef __attribute__((ext_vector_type(8))) __bf16 bf16x8;
typedef __attribute__((ext_vector_type(4))) __bf16 bf16x4;
typedef __attribute__((ext_vector_type(4))) float f32x4;
typedef __attribute__((ext_vector_type(16))) float f32x16;
typedef __attribute__((ext_vector_type(8))) unsigned short u16x8;
typedef __attribute__((ext_vector_type(4))) unsigned int u32x4;

typedef __attribute__((address_space(3))) unsigned int lds_u32;
typedef const __attribute__((address_space(1))) unsigned int glob_u32;
#define GLD16(g, l) __builtin_amdgcn_global_load_lds((glob_u32*)(g), (lds_u32*)(l), 16, 0, 0)

__device__ __forceinline__ unsigned pack2(float a, float b) {
  unsigned short ua = __builtin_bit_cast(unsigned short, (__bf16)a);
  unsigned short ub = __builtin_bit_cast(unsigned short, (__bf16)b);
  return (unsigned)ua | ((unsigned)ub << 16);
}

// ---------------- fused prep: 4 weight transposes + x convert, one launch ----------------
__global__ __launch_bounds__(256) void prep_k(const float* __restrict__ w_qkv,
                                              const float* __restrict__ w_out,
                                              const float* __restrict__ w1,
                                              const float* __restrict__ w2,
                                              const float* __restrict__ x,
                                              __hip_bfloat16* __restrict__ wqT,
                                              __hip_bfloat16* __restrict__ woT,
                                              __hip_bfloat16* __restrict__ w1T,
                                              __hip_bfloat16* __restrict__ w2T,
                                              __hip_bfloat16* __restrict__ xb) {
  const int id = blockIdx.x;
  if (id >= 8192) {                     // x f32 -> bf16
    const size_t base = ((size_t)(id - 8192) * 256 + threadIdx.x) * 8;
    float4 a = *reinterpret_cast<const float4*>(x + base);
    float4 b = *reinterpret_cast<const float4*>(x + base + 4);
    bf16x8 o;
    o[0] = (__bf16)a.x; o[1] = (__bf16)a.y; o[2] = (__bf16)a.z; o[3] = (__bf16)a.w;
    o[4] = (__bf16)b.x; o[5] = (__bf16)b.y; o[6] = (__bf16)b.z; o[7] = (__bf16)b.w;
    *reinterpret_cast<bf16x8*>(xb + base) = o;
    return;
  }
  const float* W; __hip_bfloat16* WT; int K, N, kb, nb;
  if (id < 3072)      { W = w_qkv; WT = wqT; K = 1024; N = 3072; kb = id & 31;          nb = id >> 5; }
  else if (id < 4096) { W = w_out; WT = woT; K = 1024; N = 1024; kb = (id - 3072) & 31; nb = (id - 3072) >> 5; }
  else if (id < 6144) { W = w1;    WT = w1T; K = 1024; N = 2048; kb = (id - 4096) & 31; nb = (id - 4096) >> 5; }
  else                { W = w2;    WT = w2T; K = 2048; N = 1024; kb = (id - 6144) & 63; nb = (id - 6144) >> 6; }
  __shared__ float tsm[32][33];
  const int k0 = kb * 32, n0 = nb * 32;
  const int c = threadIdx.x & 31, r = threadIdx.x >> 5;
#pragma unroll
  for (int i = 0; i < 4; ++i)
    tsm[r + 8 * i][c] = W[(size_t)(k0 + r + 8 * i) * N + n0 + c];
  __syncthreads();
#pragma unroll
  for (int i = 0; i < 4; ++i)
    WT[(size_t)(n0 + r + 8 * i) * K + k0 + c] = __float2bfloat16(tsm[c][r + 8 * i]);
}

// ---------------- GEMM (m97 structure): C = A[M,K] @ BT[N,K]^T ----------------
// EPI: 0 none, 1 +bias, 2 +bias+gelu. OUTB: bf16/f32 out. HASRES: += RES[row][col]
template<int EPI, int OUTB, int HASRES>
__global__ __launch_bounds__(256) void gemm2(const __hip_bfloat16* __restrict__ A,
                                             const __hip_bfloat16* __restrict__ BT,
                                             const float* __restrict__ bias,
                                             float* __restrict__ Cf,
                                             __hip_bfloat16* __restrict__ Cb,
                                             const float* __restrict__ RES,
                                             int M, int N, int K) {
  __shared__ __align__(16) __hip_bfloat16 As[128 * 32];
  __shared__ __align__(16) __hip_bfloat16 Bs[128 * 32];
  const int tid  = threadIdx.x;
  const int lane = tid & 63, wave = tid >> 6;
  const int wr = wave >> 1, wc = wave & 1;
  const int lr = lane & 15, lq = lane >> 4;
  const int bm0 = blockIdx.y * 128, bn0 = blockIdx.x * 128;
  f32x4 acc[4][4] = {};

  for (int k0 = 0; k0 < K; k0 += 32) {
#pragma unroll
    for (int j = 0; j < 2; ++j) {
      const int cbase = j * 256 + wave * 64;
      const int c = cbase + lane;
      const int row = c >> 2, kq = (c & 3) * 8;
      GLD16(A  + (size_t)(bm0 + row) * K + k0 + kq, (char*)As + cbase * 16);
      GLD16(BT + (size_t)(bn0 + row) * K + k0 + kq, (char*)Bs + cbase * 16);
    }
    __syncthreads();
    bf16x8 af[4], bfr[4];
#pragma unroll
    for (int i = 0; i < 4; ++i)
      af[i] = *reinterpret_cast<const bf16x8*>(As + (wr * 64 + i * 16 + lr) * 32 + lq * 8);
#pragma unroll
    for (int i = 0; i < 4; ++i)
      bfr[i] = *reinterpret_cast<const bf16x8*>(Bs + (wc * 64 + i * 16 + lr) * 32 + lq * 8);
#pragma unroll
    for (int mi = 0; mi < 4; ++mi)
#pragma unroll
      for (int ni = 0; ni < 4; ++ni)
        acc[mi][ni] = __builtin_amdgcn_mfma_f32_16x16x32_bf16(af[mi], bfr[ni], acc[mi][ni], 0, 0, 0);
    __syncthreads();
  }

#pragma unroll
  for (int mi = 0; mi < 4; ++mi) {
#pragma unroll
    for (int ni = 0; ni < 4; ++ni) {
      const int col = bn0 + wc * 64 + ni * 16 + lr;
      const float bv = (EPI >= 1) ? bias[col] : 0.0f;
#pragma unroll
      for (int j = 0; j < 4; ++j) {
        const int row = bm0 + wr * 64 + mi * 16 + lq * 4 + j;
        float v = acc[mi][ni][j] + bv;
        if (HASRES) v += RES[(size_t)row * N + col];
        if (EPI == 2) v = 0.5f * v * (1.0f + erff(v * 0.70710678118654752f));
        if (OUTB) Cb[(size_t)row * N + col] = __float2bfloat16(v);
        else      Cf[(size_t)row * N + col] = v;
      }
    }
  }
}

// ---------------- causal flash attention v3: 32x32 swapped-operand, double-buffered ----------------
#define QK_BLOCK(sv, rowoff)                                                        \
  _Pragma("unroll")                                                                 \
  for (int ci = 0; ci < 4; ++ci) {                                                  \
    const int so = (((2 * ci + hi) ^ (lq32 & 7)) << 4);                             \
    bf16x8 ka = *reinterpret_cast<const bf16x8*>(Kcur + ((rowoff) + lq32) * 128 + so);\
    sv = __builtin_amdgcn_mfma_f32_32x32x16_bf16(ka, qf[ci], sv, 0, 0, 0);          \
  }

#define DIAG_MASK(sv)                                                               \
  _Pragma("unroll")                                                                 \
  for (int r = 0; r < 16; ++r) {                                                    \
    const int kl = (r & 3) + 8 * (r >> 2) + 4 * hi;                                 \
    if (kl > lq32) sv[r] = -1e30f;                                                  \
  }

#define EXP_SUM(sv)                                                                 \
  _Pragma("unroll")                                                                 \
  for (int r = 0; r < 16; ++r) {                                                    \
    sv[r] = __builtin_amdgcn_exp2f(fmaf(sv[r], RL, mneg));                          \
    rs += sv[r];                                                                    \
  }

#define PV_HALF(wl0, wl1, wh0, wh1, ksg)                                            \
  {                                                                                 \
    unsigned t0_ = hi ? (wl0) : (wh0);                                              \
    unsigned t1_ = hi ? (wl1) : (wh1);                                              \
    t0_ = (unsigned)__shfl_xor((int)t0_, 32);                                       \
    t1_ = (unsigned)__shfl_xor((int)t1_, 32);                                       \
    u32x4 fw;                                                                       \
    fw[0] = hi ? t0_ : (wl0);  fw[1] = hi ? t1_ : (wl1);                            \
    fw[2] = hi ? (wh0) : t0_;  fw[3] = hi ? (wh1) : t1_;                            \
    bf16x8 pf = __builtin_bit_cast(bf16x8, fw);                                     \
    const int so0 = (((2 * (ksg) + hi) ^ xs0) << 4);                                \
    bf16x8 va = *reinterpret_cast<const bf16x8*>(Vcur + lq32 * 128 + so0);          \
    o0 = __builtin_amdgcn_mfma_f32_32x32x16_bf16(va, pf, o0, 0, 0, 0);              \
    const int so1 = (((2 * (ksg) + hi) ^ xs1) << 4);                                \
    bf16x8 vb = *reinterpret_cast<const bf16x8*>(Vcur + (32 + lq32) * 128 + so1);   \
    o1 = __builtin_amdgcn_mfma_f32_32x32x16_bf16(vb, pf, o1, 0, 0, 0);              \
  }

#define PV_BLOCK(sv, kb)                                                            \
  {                                                                                 \
    unsigned w0_ = pack2(sv[0], sv[1]),   w1_ = pack2(sv[2], sv[3]);                \
    unsigned w2_ = pack2(sv[4], sv[5]),   w3_ = pack2(sv[6], sv[7]);                \
    unsigned w4_ = pack2(sv[8], sv[9]),   w5_ = pack2(sv[10], sv[11]);              \
    unsigned w6_ = pack2(sv[12], sv[13]), w7_ = pack2(sv[14], sv[15]);              \
    PV_HALF(w0_, w1_, w2_, w3_, 2 * (kb))                                           \
    PV_HALF(w4_, w5_, w6_, w7_, 2 * (kb) + 1)                                       \
  }

#define V_LOAD(t_)                                                                  \
  {                                                                                 \
    const __hip_bfloat16* vp_ = qkv + rowbase + (size_t)((t_) * 64 + 2 * kp) * QKV_LD \
                                + 2 * DM + h * HDIM + d8 * 8;                       \
    vv0 = *reinterpret_cast<const u16x8*>(vp_);                                     \
    vv1 = *reinterpret_cast<const u16x8*>(vp_ + QKV_LD);                            \
  }

#define K_GLD(t_, dst)                                                              \
  _Pragma("unroll")                                                                 \
  for (int j_ = 0; j_ < 2; ++j_) {                                                  \
    const int cbase_ = j_ * 256 + wave * 64;                                        \
    const int c_ = cbase_ + lane;                                                   \
    const int key_ = c_ >> 3, slot_ = c_ & 7;                                       \
    const int gch_ = slot_ ^ (key_ & 7);                                            \
    GLD16(qkv + rowbase + (size_t)((t_) * 64 + key_) * QKV_LD + DM + h * HDIM + gch_ * 8, \
          (dst) + cbase_ * 16);                                                     \
  }

#define V_WRITE(dst)                                                                \
  _Pragma("unroll")                                                                 \
  for (int i_ = 0; i_ < 8; ++i_) {                                                  \
    const int d_ = d8 * 8 + i_;                                                     \
    const unsigned pk_ = (unsigned)vv0[i_] | ((unsigned)vv1[i_] << 16);             \
    const int x_ = ((d_ >> 3) ^ ((d_ & 1) << 2)) & 7;                               \
    const int bo_ = (d_ * 128 + kp * 4) ^ (x_ << 4);                                \
    *reinterpret_cast<unsigned*>((dst) + bo_) = pk_;                                \
  }

__global__ __launch_bounds__(256) void attn_k(const __hip_bfloat16* __restrict__ qkv,
                                              __hip_bfloat16* __restrict__ outb) {
  const int qt = 15 - blockIdx.y;               // heavy q-tiles first
  const int b = blockIdx.x >> 4, h = blockIdx.x & 15;
  __shared__ __align__(16) __hip_bfloat16 Ks[2][64 * 64];
  __shared__ __align__(16) __hip_bfloat16 Vt[2][64 * 64];
  const int tid  = threadIdx.x;
  const int lane = tid & 63, wave = tid >> 6;
  const int lq32 = lane & 31, hi = lane >> 5;
  const int qb = qt * 128 + wave * 32;
  const int qg = qb + lq32;
  const size_t rowbase = (size_t)(b * L_SEQ) * QKV_LD;
  const int xs0 = ((lq32 >> 3) ^ ((lq32 & 1) << 2)) & 7;
  const int xs1 = (((32 + lq32) >> 3) ^ ((lq32 & 1) << 2)) & 7;
  const int kp = tid >> 3, d8 = tid & 7;        // V staging coords

  // Q B-frags: lane holds Q[qg][16c + 8hi + j]
  bf16x8 qf[4];
  {
    const __hip_bfloat16* qp = qkv + rowbase + (size_t)qg * QKV_LD + h * HDIM + 8 * hi;
#pragma unroll
    for (int c = 0; c < 4; ++c)
      qf[c] = *reinterpret_cast<const bf16x8*>(qp + 16 * c);
  }

  f32x16 o0 = {}, o1 = {};
  float m = -1e30f, lsum = 0.0f;
  u16x8 vv0, vv1;

  const int ntiles = 2 * qt + 2;

  // prologue: stage tile 0 into buffer 0
  V_LOAD(0)
  K_GLD(0, (char*)Ks[0])
  V_WRITE((char*)Vt[0])
  __syncthreads();

  for (int t = 0; t < ntiles; ++t) {
    const int k0 = t * 64;
    char* const Kcur = (char*)Ks[t & 1];
    char* const Vcur = (char*)Vt[t & 1];
    char* const Knxt = (char*)Ks[(t & 1) ^ 1];
    char* const Vnxt = (char*)Vt[(t & 1) ^ 1];
    const bool pf = (t + 1 < ntiles);
    if (pf) {                                   // issue next-tile loads EARLY
      V_LOAD(t + 1)
      K_GLD(t + 1, Knxt)
    }

    if (k0 <= qb + 31) {                        // wave has live keys in this tile
      float rs = 0.0f;
      if (k0 < qb) {
        f32x16 s0 = {}, s1 = {};
        __builtin_amdgcn_s_setprio(1);
        QK_BLOCK(s0, 0)
        QK_BLOCK(s1, 32)
        __builtin_amdgcn_s_setprio(0);
        if (k0 + 32 == qb) { DIAG_MASK(s1) }
        float tm = s0[0];
#pragma unroll
        for (int r = 1; r < 16; ++r) tm = fmaxf(tm, s0[r]);
#pragma unroll
        for (int r = 0; r < 16; ++r) tm = fmaxf(tm, s1[r]);
        tm = fmaxf(tm, __shfl_xor(tm, 32));
        if (!__all(tm <= m)) {
          const float mn = fmaxf(m, tm);
          const float fac = __builtin_amdgcn_exp2f((m - mn) * RL);
          m = mn; lsum *= fac; o0 *= fac; o1 *= fac;
        }
        const float mneg = -m * RL;
        EXP_SUM(s0)
        EXP_SUM(s1)
        rs += __shfl_xor(rs, 32);
        lsum += rs;
        __builtin_amdgcn_s_setprio(1);
        PV_BLOCK(s0, 0)
        PV_BLOCK(s1, 1)
        __builtin_amdgcn_s_setprio(0);
      } else {                                  // k0 == qb: single diagonal block
        f32x16 s0 = {};
        __builtin_amdgcn_s_setprio(1);
        QK_BLOCK(s0, 0)
        __builtin_amdgcn_s_setprio(0);
        DIAG_MASK(s0)
        float tm = s0[0];
#pragma unroll
        for (int r = 1; r < 16; ++r) tm = fmaxf(tm, s0[r]);
        tm = fmaxf(tm, __shfl_xor(tm, 32));
        if (!__all(tm <= m)) {
          const float mn = fmaxf(m, tm);
          const float fac = __builtin_amdgcn_exp2f((m - mn) * RL);
          m = mn; lsum *= fac; o0 *= fac; o1 *= fac;
        }
        const float mneg = -m * RL;
        EXP_SUM(s0)
        rs += __shfl_xor(rs, 32);
        lsum += rs;
        __builtin_amdgcn_s_setprio(1);
        PV_BLOCK(s0, 0)
        __builtin_amdgcn_s_setprio(0);
      }
    }

    if (pf) V_WRITE(Vnxt)                       // write-late: V regs landed under compute
    __syncthreads();
  }

  // epilogue: lane owns col q=qg, rows d = (r&3)+8(r>>2)+4hi (+32 for o1)
  const float inv = 1.0f / lsum;
  __hip_bfloat16* orow = outb + (size_t)(b * L_SEQ + qg) * DM + h * HDIM + 4 * hi;
#pragma unroll
  for (int rg = 0; rg < 4; ++rg) {
    bf16x4 ov;
#pragma unroll
    for (int i = 0; i < 4; ++i) ov[i] = (__bf16)(o0[4 * rg + i] * inv);
    *reinterpret_cast<bf16x4*>(orow + 8 * rg) = ov;
#pragma unroll
    for (int i = 0; i < 4; ++i) ov[i] = (__bf16)(o1[4 * rg + i] * inv);
    *reinterpret_cast<bf16x4*>(orow + 32 + 8 * rg) = ov;
  }
}

// ---------------- LayerNorm: Y = LN(X) * g + be (X already has residual) ----------------
template<int WB>
__global__ __launch_bounds__(256) void ln_k(const float* __restrict__ X,
                                            const float* __restrict__ g,
                                            const float* __restrict__ be,
                                            float* __restrict__ Y,
                                            __hip_bfloat16* __restrict__ Yb) {
  const int row = blockIdx.x;
  const int tid = threadIdx.x;
  const int lane = tid & 63, wave = tid >> 6;
  float4 x4 = *reinterpret_cast<const float4*>(X + (size_t)row * DM + tid * 4);
  float v0 = x4.x, v1 = x4.y, v2 = x4.z, v3 = x4.w;
  float s  = v0 + v1 + v2 + v3;
  float ss = v0 * v0 + v1 * v1 + v2 * v2 + v3 * v3;
#pragma unroll
  for (int off = 1; off < 64; off <<= 1) {
    s  += __shfl_xor(s, off);
    ss += __shfl_xor(ss, off);
  }
  __shared__ float red[8];
  if (lane == 0) { red[wave] = s; red[4 + wave] = ss; }
  __syncthreads();
  float S  = red[0] + red[1] + red[2] + red[3];
  float SS = red[4] + red[5] + red[6] + red[7];
  float mu  = S * (1.0f / DM);
  float var = SS * (1.0f / DM) - mu * mu;
  float rsd = rsqrtf(var + 1e-5f);
  float4 gv = *reinterpret_cast<const float4*>(g + tid * 4);
  float4 bv = *reinterpret_cast<const float4*>(be + tid * 4);
  float4 y;
  y.x = (v0 - mu) * rsd * gv.x + bv.x;
  y.y = (v1 - mu) * rsd * gv.y + bv.y;
  y.z = (v2 - mu) * rsd * gv.z + bv.z;
  y.w = (v3 - mu) * rsd * gv.w + bv.w;
  *reinterpret_cast<float4*>(Y + (size_t)row * DM + tid * 4) = y;
  if (WB) {
    bf16x4 yb;
    yb[0] = (__bf16)y.x; yb[1] = (__bf16)y.y; yb[2] = (__bf16)y.z; yb[3] = (__bf16)y.w;
    *reinterpret_cast<bf16x4*>(Yb + (size_t)row * DM + tid * 4) = yb;
  }
}

extern "C" void kernel_launch(void* const* d_in, const int* in_sizes, int n_in,
                              void* d_out, int out_size, void* d_ws, size_t ws_size,
                              hipStream_t stream) {
  const float* x     = (const float*)d_in[0];
  const float* w_qkv = (const float*)d_in[1];
  const float* w_out = (const float*)d_in[2];
  const float* w1    = (const float*)d_in[3];
  const float* b1    = (const float*)d_in[4];
  const float* w2    = (const float*)d_in[5];
  const float* b2    = (const float*)d_in[6];
  const float* g1    = (const float*)d_in[7];
  const float* be1   = (const float*)d_in[8];
  const float* g2    = (const float*)d_in[9];
  const float* be2   = (const float*)d_in[10];
  float* outp = (float*)d_out;
  char* base  = (char*)d_ws;
  const int M = NB * L_SEQ;                 // 4096

  __hip_bfloat16* w2T  = (__hip_bfloat16*)(base + 0);          // [1024][2048]
  __hip_bfloat16* woT  = (__hip_bfloat16*)(base + 4194304);    // [1024][1024]
  __hip_bfloat16* w1T  = (__hip_bfloat16*)(base + 6291456);    // [2048][1024]
  __hip_bfloat16* wqT  = (__hip_bfloat16*)(base + 10485760);   // [3072][1024]
  __hip_bfloat16* xb   = (__hip_bfloat16*)(base + 16777216);   // [4096][1024]
  __hip_bfloat16* attnb= xb;                                   // reuse after qkv GEMM
  __hip_bfloat16* qkvb = (__hip_bfloat16*)(base + 25165824);   // [4096][3072]
  __hip_bfloat16* ffh  = (__hip_bfloat16*)(base + 25165824);   // [4096][2048] (qkvb dead)
  __hip_bfloat16* ln1b = (__hip_bfloat16*)(base + 41943040);   // [4096][1024] (qkvb dead)
  float*          ffo  = (float*)(base + 8388608);             // [4096][1024] f32
  float*          ln1f = (float*)(base + 50331648);            // [4096][1024] f32
  float*          proj = outp;                                 // d_out as scratch

  // fused prep: all weight transposes + x convert
  prep_k<<<10240, 256, 0, stream>>>(w_qkv, w_out, w1, w2, x, wqT, woT, w1T, w2T, xb);

  // 1. qkv = x @ w_qkv (bf16)
  gemm2<0, 1, 0><<<dim3(24, 32), 256, 0, stream>>>(xb, wqT, nullptr, nullptr, qkvb, nullptr, M, QKV_LD, DM);
  // 2. attention (bf16)
  attn_k<<<dim3(32, 16), 256, 0, stream>>>(qkvb, attnb);
  // 3. proj = attn @ w_out + x  (f32, residual fused)
  gemm2<0, 0, 1><<<dim3(8, 32), 256, 0, stream>>>(attnb, woT, nullptr, proj, nullptr, x, M, DM, DM);
  // 4. ln1 = LN(proj)
  ln_k<1><<<M, 256, 0, stream>>>(proj, g1, be1, ln1f, ln1b);
  // 5. ffh = gelu(ln1 @ w1 + b1) (bf16)
  gemm2<2, 1, 0><<<dim3(16, 32), 256, 0, stream>>>(ln1b, w1T, b1, nullptr, ffh, nullptr, M, 2 * DM, DM);
  // 6. ffo = ffh @ w2 + b2 + ln1 (f32, residual fused)
  gemm2<1, 0, 1><<<dim3(8, 32), 256, 0, stream>>>(ffh, w2T, b2, ffo, nullptr, ln1f, M, DM, 2 * DM);
  // 7. out = LN(ffo)
  ln_k<0><<<M, 256, 0, stream>>>(ffo, g2, be2, outp, nullptr);
}

// Round 5
// 236.224 us; speedup vs baseline: 2.7500x; 1.0246x over previous
//
#include <hip/hip_runtime.h>
#include <hip/hip_bf16.h>
#include <math.h>

#define L_SEQ 2048
#define NB 2
#define DM 1024
#define NHEAD 16
#define HDIM 64
#define QKV_LD 3072
#define RL 0.18033688011112042f   // 0.125 * log2(e)
#define DTHR 44.3614f             // 8 / RL  (defer-max threshold in raw score units)

typedef __attribute__((ext_vector_type(8))) __bf16 bf16x8;
typedef __attribute__((ext_vector_type(4))) __bf16 bf16x4;
typedef __attribute__((ext_vector_type(4))) float f32x4;
typedef __attribute__((ext_vector_type(16))) float f32x16;
typedef __attribute__((ext_vector_type(8))) unsigned short u16x8;
typedef __attribute__((ext_vector_type(4))) unsigned int u32x4;

typedef __attribute__((address_space(3))) unsigned int lds_u32;
typedef const __attribute__((address_space(1))) unsigned int glob_u32;
#define GLD16(g, l) __builtin_amdgcn_global_load_lds((glob_u32*)(g), (lds_u32*)(l), 16, 0, 0)

__device__ __forceinline__ unsigned pack2(float a, float b) {
  unsigned short ua = __builtin_bit_cast(unsigned short, (__bf16)a);
  unsigned short ub = __builtin_bit_cast(unsigned short, (__bf16)b);
  return (unsigned)ua | ((unsigned)ub << 16);
}

// ---------------- fused prep: 4 weight transposes + x convert ----------------
__global__ __launch_bounds__(256) void prep_k(const float* __restrict__ w_qkv,
                                              const float* __restrict__ w_out,
                                              const float* __restrict__ w1,
                                              const float* __restrict__ w2,
                                              const float* __restrict__ x,
                                              __hip_bfloat16* __restrict__ wqT,
                                              __hip_bfloat16* __restrict__ woT,
                                              __hip_bfloat16* __restrict__ w1T,
                                              __hip_bfloat16* __restrict__ w2T,
                                              __hip_bfloat16* __restrict__ xb) {
  const int id = blockIdx.x;
  if (id >= 8192) {                     // x f32 -> bf16
    const size_t base = ((size_t)(id - 8192) * 256 + threadIdx.x) * 8;
    float4 a = *reinterpret_cast<const float4*>(x + base);
    float4 b = *reinterpret_cast<const float4*>(x + base + 4);
    bf16x8 o;
    o[0] = (__bf16)a.x; o[1] = (__bf16)a.y; o[2] = (__bf16)a.z; o[3] = (__bf16)a.w;
    o[4] = (__bf16)b.x; o[5] = (__bf16)b.y; o[6] = (__bf16)b.z; o[7] = (__bf16)b.w;
    *reinterpret_cast<bf16x8*>(xb + base) = o;
    return;
  }
  const float* W; __hip_bfloat16* WT; int K, N, kb, nb;
  if (id < 3072)      { W = w_qkv; WT = wqT; K = 1024; N = 3072; kb = id & 31;          nb = id >> 5; }
  else if (id < 4096) { W = w_out; WT = woT; K = 1024; N = 1024; kb = (id - 3072) & 31; nb = (id - 3072) >> 5; }
  else if (id < 6144) { W = w1;    WT = w1T; K = 1024; N = 2048; kb = (id - 4096) & 31; nb = (id - 4096) >> 5; }
  else                { W = w2;    WT = w2T; K = 2048; N = 1024; kb = (id - 6144) & 63; nb = (id - 6144) >> 6; }
  __shared__ float tsm[32][33];
  const int k0 = kb * 32, n0 = nb * 32;
  const int c = threadIdx.x & 31, r = threadIdx.x >> 5;
#pragma unroll
  for (int i = 0; i < 4; ++i)
    tsm[r + 8 * i][c] = W[(size_t)(k0 + r + 8 * i) * N + n0 + c];
  __syncthreads();
#pragma unroll
  for (int i = 0; i < 4; ++i)
    WT[(size_t)(n0 + r + 8 * i) * K + k0 + c] = __float2bfloat16(tsm[c][r + 8 * i]);
}

// ---------------- GEMM (m97 structure): C = A[M,K] @ BT[N,K]^T ----------------
template<int EPI, int OUTB, int HASRES>
__global__ __launch_bounds__(256) void gemm2(const __hip_bfloat16* __restrict__ A,
                                             const __hip_bfloat16* __restrict__ BT,
                                             const float* __restrict__ bias,
                                             float* __restrict__ Cf,
                                             __hip_bfloat16* __restrict__ Cb,
                                             const float* __restrict__ RES,
                                             int M, int N, int K) {
  __shared__ __align__(16) __hip_bfloat16 As[128 * 32];
  __shared__ __align__(16) __hip_bfloat16 Bs[128 * 32];
  const int tid  = threadIdx.x;
  const int lane = tid & 63, wave = tid >> 6;
  const int wr = wave >> 1, wc = wave & 1;
  const int lr = lane & 15, lq = lane >> 4;
  const int bm0 = blockIdx.y * 128, bn0 = blockIdx.x * 128;
  f32x4 acc[4][4] = {};

  for (int k0 = 0; k0 < K; k0 += 32) {
#pragma unroll
    for (int j = 0; j < 2; ++j) {
      const int cbase = j * 256 + wave * 64;
      const int c = cbase + lane;
      const int row = c >> 2, kq = (c & 3) * 8;
      GLD16(A  + (size_t)(bm0 + row) * K + k0 + kq, (char*)As + cbase * 16);
      GLD16(BT + (size_t)(bn0 + row) * K + k0 + kq, (char*)Bs + cbase * 16);
    }
    __syncthreads();
    bf16x8 af[4], bfr[4];
#pragma unroll
    for (int i = 0; i < 4; ++i)
      af[i] = *reinterpret_cast<const bf16x8*>(As + (wr * 64 + i * 16 + lr) * 32 + lq * 8);
#pragma unroll
    for (int i = 0; i < 4; ++i)
      bfr[i] = *reinterpret_cast<const bf16x8*>(Bs + (wc * 64 + i * 16 + lr) * 32 + lq * 8);
#pragma unroll
    for (int mi = 0; mi < 4; ++mi)
#pragma unroll
      for (int ni = 0; ni < 4; ++ni)
        acc[mi][ni] = __builtin_amdgcn_mfma_f32_16x16x32_bf16(af[mi], bfr[ni], acc[mi][ni], 0, 0, 0);
    __syncthreads();
  }

#pragma unroll
  for (int mi = 0; mi < 4; ++mi) {
#pragma unroll
    for (int ni = 0; ni < 4; ++ni) {
      const int col = bn0 + wc * 64 + ni * 16 + lr;
      const float bv = (EPI >= 1) ? bias[col] : 0.0f;
#pragma unroll
      for (int j = 0; j < 4; ++j) {
        const int row = bm0 + wr * 64 + mi * 16 + lq * 4 + j;
        float v = acc[mi][ni][j] + bv;
        if (HASRES) v += RES[(size_t)row * N + col];
        if (EPI == 2) v = 0.5f * v * (1.0f + erff(v * 0.70710678118654752f));
        if (OUTB) Cb[(size_t)row * N + col] = __float2bfloat16(v);
        else      Cf[(size_t)row * N + col] = v;
      }
    }
  }
}

// ---------------- causal flash attention v4: in-block split-K, no in-loop barriers ----------------
// Block: 32 q-rows, 4 waves each taking key-tiles t%4==wave (KVBLK=32).
// Per wave: swapped QK (S^T = K @ Q^T, lane owns one q-row), K direct from global
// (L2-resident), V staged transposed in wave-private LDS. Partials merged at end.

#define DIAG_MASK(sv)                                                               \
  _Pragma("unroll")                                                                 \
  for (int r = 0; r < 16; ++r) {                                                    \
    const int kl = (r & 3) + 8 * (r >> 2) + 4 * hi;                                 \
    if (kl > lq32) sv[r] = -1e30f;                                                  \
  }

#define PV_HALF(wl0, wl1, wh0, wh1, ksg)                                            \
  {                                                                                 \
    unsigned t0_ = hi ? (wl0) : (wh0);                                              \
    unsigned t1_ = hi ? (wl1) : (wh1);                                              \
    t0_ = (unsigned)__shfl_xor((int)t0_, 32);                                       \
    t1_ = (unsigned)__shfl_xor((int)t1_, 32);                                       \
    u32x4 fw;                                                                       \
    fw[0] = hi ? t0_ : (wl0);  fw[1] = hi ? t1_ : (wl1);                            \
    fw[2] = hi ? (wh0) : t0_;  fw[3] = hi ? (wh1) : t1_;                            \
    bf16x8 pfb = __builtin_bit_cast(bf16x8, fw);                                    \
    bf16x8 vA = *reinterpret_cast<const bf16x8*>(Vw + lq32 * 80 + 32 * (ksg) + 16 * hi);        \
    o0 = __builtin_amdgcn_mfma_f32_32x32x16_bf16(vA, pfb, o0, 0, 0, 0);             \
    bf16x8 vB = *reinterpret_cast<const bf16x8*>(Vw + (32 + lq32) * 80 + 32 * (ksg) + 16 * hi); \
    o1 = __builtin_amdgcn_mfma_f32_32x32x16_bf16(vB, pfb, o1, 0, 0, 0);             \
  }

__global__ __launch_bounds__(256, 4) void attn_k(const __hip_bfloat16* __restrict__ qkv,
                                                 __hip_bfloat16* __restrict__ outb) {
  __shared__ __align__(16) char smem[4 * 8192 + 2048];
  // XCD-aware swizzle: xcd = bid%8 owns 4 heads; heavy q-blocks dispatched first
  const int bid = blockIdx.x;
  const int seq = bid >> 3;
  const int bh  = (bid & 7) * 4 + (seq & 3);     // 0..31
  const int qt32 = 63 - (seq >> 2);              // 0..63, heavy first
  const int b = bh >> 4, h = bh & 15;
  const int qb = qt32 * 32;
  const int tid = threadIdx.x;
  const int lane = tid & 63, wave = tid >> 6;
  const int lq32 = lane & 31, hi = lane >> 5;
  const int kg = lane >> 3, d8 = lane & 7;       // V staging: keys 4kg..4kg+3, d-slice d8*8..
  const size_t rowbase = (size_t)(b * L_SEQ) * QKV_LD;
  char* const Vw = smem + wave * 8192;           // wave-private V^T [64 d][80B rows]
  float* const ML = (float*)(smem + 32768);

  // Q B-frags: lane holds Q[qb+lq32][16c + 8hi + j]
  bf16x8 qf[4];
  {
    const __hip_bfloat16* qp = qkv + rowbase + (size_t)(qb + lq32) * QKV_LD + h * HDIM + 8 * hi;
#pragma unroll
    for (int c = 0; c < 4; ++c) qf[c] = *reinterpret_cast<const bf16x8*>(qp + 16 * c);
  }

  f32x16 o0 = {}, o1 = {};
  float m = -1e30f, lsum = 0.0f;

  for (int t = wave; t <= qt32; t += 4) {
    const int k0 = t * 32;
    // ---- K fragments: direct global (L2-resident) ----
    const __hip_bfloat16* kp = qkv + rowbase + (size_t)(k0 + lq32) * QKV_LD + DM + h * HDIM + 8 * hi;
    bf16x8 ka0 = *reinterpret_cast<const bf16x8*>(kp);
    bf16x8 ka1 = *reinterpret_cast<const bf16x8*>(kp + 16);
    bf16x8 ka2 = *reinterpret_cast<const bf16x8*>(kp + 32);
    bf16x8 ka3 = *reinterpret_cast<const bf16x8*>(kp + 48);
    // ---- V tile load (4 key rows x 8 d) ----
    const __hip_bfloat16* vp = qkv + rowbase + (size_t)(k0 + 4 * kg) * QKV_LD + 2 * DM + h * HDIM + d8 * 8;
    u16x8 va_ = *reinterpret_cast<const u16x8*>(vp);
    u16x8 vb_ = *reinterpret_cast<const u16x8*>(vp + QKV_LD);
    u16x8 vc_ = *reinterpret_cast<const u16x8*>(vp + 2 * QKV_LD);
    u16x8 vd_ = *reinterpret_cast<const u16x8*>(vp + 3 * QKV_LD);
    // ---- V^T -> wave-private LDS ----
#pragma unroll
    for (int i = 0; i < 8; ++i) {
      const int d = d8 * 8 + i;
      uint2 pk;
      pk.x = (unsigned)va_[i] | ((unsigned)vb_[i] << 16);
      pk.y = (unsigned)vc_[i] | ((unsigned)vd_[i] << 16);
      *reinterpret_cast<uint2*>(Vw + d * 80 + kg * 8) = pk;
    }
    // ---- QK ----
    f32x16 s = {};
    s = __builtin_amdgcn_mfma_f32_32x32x16_bf16(ka0, qf[0], s, 0, 0, 0);
    s = __builtin_amdgcn_mfma_f32_32x32x16_bf16(ka1, qf[1], s, 0, 0, 0);
    s = __builtin_amdgcn_mfma_f32_32x32x16_bf16(ka2, qf[2], s, 0, 0, 0);
    s = __builtin_amdgcn_mfma_f32_32x32x16_bf16(ka3, qf[3], s, 0, 0, 0);
    if (t == qt32) { DIAG_MASK(s) }
    // ---- online softmax (tree max, defer-rescale THR) ----
    float a0 = fmaxf(s[0], s[1]),   a1 = fmaxf(s[2], s[3]);
    float a2 = fmaxf(s[4], s[5]),   a3 = fmaxf(s[6], s[7]);
    float a4 = fmaxf(s[8], s[9]),   a5 = fmaxf(s[10], s[11]);
    float a6 = fmaxf(s[12], s[13]), a7 = fmaxf(s[14], s[15]);
    a0 = fmaxf(a0, a1); a2 = fmaxf(a2, a3); a4 = fmaxf(a4, a5); a6 = fmaxf(a6, a7);
    float tm = fmaxf(fmaxf(a0, a2), fmaxf(a4, a6));
    tm = fmaxf(tm, __shfl_xor(tm, 32));
    if (!__all(tm <= m + DTHR)) {
      const float mn = fmaxf(m, tm);
      const float fac = __builtin_amdgcn_exp2f((m - mn) * RL);
      m = mn; lsum *= fac; o0 *= fac; o1 *= fac;
    }
    const float mneg = -m * RL;
    float rs = 0.0f;
#pragma unroll
    for (int r = 0; r < 16; ++r) {
      s[r] = __builtin_amdgcn_exp2f(fmaf(s[r], RL, mneg));
      rs += s[r];
    }
    rs += __shfl_xor(rs, 32);
    lsum += rs;
    // ---- PV ----
    unsigned w0 = pack2(s[0], s[1]),   w1 = pack2(s[2], s[3]);
    unsigned w2 = pack2(s[4], s[5]),   w3 = pack2(s[6], s[7]);
    unsigned w4 = pack2(s[8], s[9]),   w5 = pack2(s[10], s[11]);
    unsigned w6 = pack2(s[12], s[13]), w7 = pack2(s[14], s[15]);
    PV_HALF(w0, w1, w2, w3, 0)
    PV_HALF(w4, w5, w6, w7, 1)
  }

  // ---- write partials (O^T into own slice, reusing V region; m,l) ----
  {
    float* Ow = (float*)Vw;
#pragma unroll
    for (int r = 0; r < 16; ++r) {
      const int d0 = (r & 3) + 8 * (r >> 2) + 4 * hi;
      Ow[d0 * 32 + lq32] = o0[r];
      Ow[(d0 + 32) * 32 + lq32] = o1[r];
    }
    if (hi == 0) {
      ML[wave * 128 + lq32] = m;
      ML[wave * 128 + 64 + lq32] = lsum;
    }
  }
  __syncthreads();

  // ---- combine 4 partials; each thread: one q (tid&31), 8 d's ----
  {
    const int q = tid & 31, dg = tid >> 5;    // dg 0..7
    const float m0 = ML[q], m1 = ML[128 + q], m2 = ML[256 + q], m3 = ML[384 + q];
    const float M = fmaxf(fmaxf(m0, m1), fmaxf(m2, m3));
    const float c0 = __builtin_amdgcn_exp2f((m0 - M) * RL);
    const float c1 = __builtin_amdgcn_exp2f((m1 - M) * RL);
    const float c2 = __builtin_amdgcn_exp2f((m2 - M) * RL);
    const float c3 = __builtin_amdgcn_exp2f((m3 - M) * RL);
    const float l = c0 * ML[64 + q] + c1 * ML[192 + q] + c2 * ML[320 + q] + c3 * ML[448 + q];
    const float inv = 1.0f / l;
    const float* OB = (const float*)smem;
    bf16x8 ov;
#pragma unroll
    for (int i = 0; i < 8; ++i) {
      const int idx = (dg * 8 + i) * 32 + q;
      const float v = c0 * OB[idx] + c1 * OB[2048 + idx] + c2 * OB[4096 + idx] + c3 * OB[6144 + idx];
      ov[i] = (__bf16)(v * inv);
    }
    *reinterpret_cast<bf16x8*>(outb + (size_t)(b * L_SEQ + qb + q) * DM + h * HDIM + dg * 8) = ov;
  }
}

// ---------------- LayerNorm: Y = LN(X) * g + be (X already has residual) ----------------
template<int WB>
__global__ __launch_bounds__(256) void ln_k(const float* __restrict__ X,
                                            const float* __restrict__ g,
                                            const float* __restrict__ be,
                                            float* __restrict__ Y,
                                            __hip_bfloat16* __restrict__ Yb) {
  const int row = blockIdx.x;
  const int tid = threadIdx.x;
  const int lane = tid & 63, wave = tid >> 6;
  float4 x4 = *reinterpret_cast<const float4*>(X + (size_t)row * DM + tid * 4);
  float v0 = x4.x, v1 = x4.y, v2 = x4.z, v3 = x4.w;
  float s  = v0 + v1 + v2 + v3;
  float ss = v0 * v0 + v1 * v1 + v2 * v2 + v3 * v3;
#pragma unroll
  for (int off = 1; off < 64; off <<= 1) {
    s  += __shfl_xor(s, off);
    ss += __shfl_xor(ss, off);
  }
  __shared__ float red[8];
  if (lane == 0) { red[wave] = s; red[4 + wave] = ss; }
  __syncthreads();
  float S  = red[0] + red[1] + red[2] + red[3];
  float SS = red[4] + red[5] + red[6] + red[7];
  float mu  = S * (1.0f / DM);
  float var = SS * (1.0f / DM) - mu * mu;
  float rsd = rsqrtf(var + 1e-5f);
  float4 gv = *reinterpret_cast<const float4*>(g + tid * 4);
  float4 bv = *reinterpret_cast<const float4*>(be + tid * 4);
  float4 y;
  y.x = (v0 - mu) * rsd * gv.x + bv.x;
  y.y = (v1 - mu) * rsd * gv.y + bv.y;
  y.z = (v2 - mu) * rsd * gv.z + bv.z;
  y.w = (v3 - mu) * rsd * gv.w + bv.w;
  *reinterpret_cast<float4*>(Y + (size_t)row * DM + tid * 4) = y;
  if (WB) {
    bf16x4 yb;
    yb[0] = (__bf16)y.x; yb[1] = (__bf16)y.y; yb[2] = (__bf16)y.z; yb[3] = (__bf16)y.w;
    *reinterpret_cast<bf16x4*>(Yb + (size_t)row * DM + tid * 4) = yb;
  }
}

extern "C" void kernel_launch(void* const* d_in, const int* in_sizes, int n_in,
                              void* d_out, int out_size, void* d_ws, size_t ws_size,
                              hipStream_t stream) {
  const float* x     = (const float*)d_in[0];
  const float* w_qkv = (const float*)d_in[1];
  const float* w_out = (const float*)d_in[2];
  const float* w1    = (const float*)d_in[3];
  const float* b1    = (const float*)d_in[4];
  const float* w2    = (const float*)d_in[5];
  const float* b2    = (const float*)d_in[6];
  const float* g1    = (const float*)d_in[7];
  const float* be1   = (const float*)d_in[8];
  const float* g2    = (const float*)d_in[9];
  const float* be2   = (const float*)d_in[10];
  float* outp = (float*)d_out;
  char* base  = (char*)d_ws;
  const int M = NB * L_SEQ;                 // 4096

  __hip_bfloat16* w2T  = (__hip_bfloat16*)(base + 0);          // [1024][2048]
  __hip_bfloat16* woT  = (__hip_bfloat16*)(base + 4194304);    // [1024][1024]
  __hip_bfloat16* w1T  = (__hip_bfloat16*)(base + 6291456);    // [2048][1024]
  __hip_bfloat16* wqT  = (__hip_bfloat16*)(base + 10485760);   // [3072][1024]
  __hip_bfloat16* xb   = (__hip_bfloat16*)(base + 16777216);   // [4096][1024]
  __hip_bfloat16* attnb= xb;                                   // reuse after qkv GEMM
  __hip_bfloat16* qkvb = (__hip_bfloat16*)(base + 25165824);   // [4096][3072]
  __hip_bfloat16* ffh  = (__hip_bfloat16*)(base + 25165824);   // [4096][2048] (qkvb dead)
  __hip_bfloat16* ln1b = (__hip_bfloat16*)(base + 41943040);   // [4096][1024] (qkvb dead)
  float*          ffo  = (float*)(base + 8388608);             // [4096][1024] f32
  float*          ln1f = (float*)(base + 50331648);            // [4096][1024] f32
  float*          proj = outp;                                 // d_out as scratch

  // fused prep: all weight transposes + x convert
  prep_k<<<10240, 256, 0, stream>>>(w_qkv, w_out, w1, w2, x, wqT, woT, w1T, w2T, xb);

  // 1. qkv = x @ w_qkv (bf16)
  gemm2<0, 1, 0><<<dim3(24, 32), 256, 0, stream>>>(xb, wqT, nullptr, nullptr, qkvb, nullptr, M, QKV_LD, DM);
  // 2. attention (bf16): 64 q-blocks x 32 bh, XCD-swizzled
  attn_k<<<2048, 256, 0, stream>>>(qkvb, attnb);
  // 3. proj = attn @ w_out + x  (f32, residual fused)
  gemm2<0, 0, 1><<<dim3(8, 32), 256, 0, stream>>>(attnb, woT, nullptr, proj, nullptr, x, M, DM, DM);
  // 4. ln1 = LN(proj)
  ln_k<1><<<M, 256, 0, stream>>>(proj, g1, be1, ln1f, ln1b);
  // 5. ffh = gelu(ln1 @ w1 + b1) (bf16)
  gemm2<2, 1, 0><<<dim3(16, 32), 256, 0, stream>>>(ln1b, w1T, b1, nullptr, ffh, nullptr, M, 2 * DM, DM);
  // 6. ffo = ffh @ w2 + b2 + ln1 (f32, residual fused)
  gemm2<1, 0, 1><<<dim3(8, 32), 256, 0, stream>>>(ffh, w2T, b2, ffo, nullptr, ln1f, M, DM, 2 * DM);
  // 7. out = LN(ffo)
  ln_k<0><<<M, 256, 0, stream>>>(ffo, g2, be2, outp, nullptr);
}

// Round 6
// 221.689 us; speedup vs baseline: 2.9303x; 1.0656x over previous
//
#include <hip/hip_runtime.h>
#include <hip/hip_bf16.h>
#include <math.h>

#define L_SEQ 2048
#define NB 2
#define DM 1024
#define NHEAD 16
#define HDIM 64
#define QKV_LD 3072
#define RL 0.18033688011112042f   // 0.125 * log2(e)
#define DTHR 44.3614f             // 8 / RL  (defer-max threshold in raw score units)

typedef __attribute__((ext_vector_type(8))) __bf16 bf16x8;
typedef __attribute__((ext_vector_type(4))) __bf16 bf16x4;
typedef __attribute__((ext_vector_type(4))) float f32x4;
typedef __attribute__((ext_vector_type(16))) float f32x16;
typedef __attribute__((ext_vector_type(4))) unsigned int u32x4;

typedef __attribute__((address_space(3))) unsigned int lds_u32;
typedef const __attribute__((address_space(1))) unsigned int glob_u32;
#define GLD16(g, l) __builtin_amdgcn_global_load_lds((glob_u32*)(g), (lds_u32*)(l), 16, 0, 0)

__device__ __forceinline__ unsigned pack2(float a, float b) {
  unsigned short ua = __builtin_bit_cast(unsigned short, (__bf16)a);
  unsigned short ub = __builtin_bit_cast(unsigned short, (__bf16)b);
  return (unsigned)ua | ((unsigned)ub << 16);
}

// ---------------- fused prep: 4 weight transposes + x convert ----------------
__global__ __launch_bounds__(256) void prep_k(const float* __restrict__ w_qkv,
                                              const float* __restrict__ w_out,
                                              const float* __restrict__ w1,
                                              const float* __restrict__ w2,
                                              const float* __restrict__ x,
                                              __hip_bfloat16* __restrict__ wqT,
                                              __hip_bfloat16* __restrict__ woT,
                                              __hip_bfloat16* __restrict__ w1T,
                                              __hip_bfloat16* __restrict__ w2T,
                                              __hip_bfloat16* __restrict__ xb) {
  const int id = blockIdx.x;
  if (id >= 8192) {                     // x f32 -> bf16
    const size_t base = ((size_t)(id - 8192) * 256 + threadIdx.x) * 8;
    float4 a = *reinterpret_cast<const float4*>(x + base);
    float4 b = *reinterpret_cast<const float4*>(x + base + 4);
    bf16x8 o;
    o[0] = (__bf16)a.x; o[1] = (__bf16)a.y; o[2] = (__bf16)a.z; o[3] = (__bf16)a.w;
    o[4] = (__bf16)b.x; o[5] = (__bf16)b.y; o[6] = (__bf16)b.z; o[7] = (__bf16)b.w;
    *reinterpret_cast<bf16x8*>(xb + base) = o;
    return;
  }
  const float* W; __hip_bfloat16* WT; int K, N, kb, nb;
  if (id < 3072)      { W = w_qkv; WT = wqT; K = 1024; N = 3072; kb = id & 31;          nb = id >> 5; }
  else if (id < 4096) { W = w_out; WT = woT; K = 1024; N = 1024; kb = (id - 3072) & 31; nb = (id - 3072) >> 5; }
  else if (id < 6144) { W = w1;    WT = w1T; K = 1024; N = 2048; kb = (id - 4096) & 31; nb = (id - 4096) >> 5; }
  else                { W = w2;    WT = w2T; K = 2048; N = 1024; kb = (id - 6144) & 63; nb = (id - 6144) >> 6; }
  __shared__ float tsm[32][33];
  const int k0 = kb * 32, n0 = nb * 32;
  const int c = threadIdx.x & 31, r = threadIdx.x >> 5;
#pragma unroll
  for (int i = 0; i < 4; ++i)
    tsm[r + 8 * i][c] = W[(size_t)(k0 + r + 8 * i) * N + n0 + c];
  __syncthreads();
#pragma unroll
  for (int i = 0; i < 4; ++i)
    WT[(size_t)(n0 + r + 8 * i) * K + k0 + c] = __float2bfloat16(tsm[c][r + 8 * i]);
}

// ---------------- GEMM (m97 structure): C = A[M,K] @ BT[N,K]^T ----------------
// EPI: 0 none, 1 +bias, 2 +bias+gelu. OUTB: bf16/f32 out. HASRES: += RES. BN: 128 or 64.
template<int EPI, int OUTB, int HASRES, int BN>
__global__ __launch_bounds__(256) void gemm2(const __hip_bfloat16* __restrict__ A,
                                             const __hip_bfloat16* __restrict__ BT,
                                             const float* __restrict__ bias,
                                             float* __restrict__ Cf,
                                             __hip_bfloat16* __restrict__ Cb,
                                             const float* __restrict__ RES,
                                             int M, int N, int K) {
  constexpr int MI = (BN == 128) ? 4 : 2;       // per-wave 16-row fragments
  __shared__ __align__(16) __hip_bfloat16 As[128 * 32];
  __shared__ __align__(16) __hip_bfloat16 Bs[BN * 32];
  const int tid  = threadIdx.x;
  const int lane = tid & 63, wave = tid >> 6;
  const int wr = (BN == 128) ? (wave >> 1) : wave;
  const int wc = (BN == 128) ? (wave & 1) : 0;
  const int lr = lane & 15, lq = lane >> 4;
  const int bm0 = blockIdx.y * 128, bn0 = blockIdx.x * BN;
  f32x4 acc[MI][4] = {};

  for (int k0 = 0; k0 < K; k0 += 32) {
#pragma unroll
    for (int j = 0; j < 2; ++j) {
      const int cbase = j * 256 + wave * 64;
      const int c = cbase + lane;
      GLD16(A + (size_t)(bm0 + (c >> 2)) * K + k0 + (c & 3) * 8, (char*)As + cbase * 16);
    }
#pragma unroll
    for (int j = 0; j < BN / 64; ++j) {
      const int cbase = j * 256 + wave * 64;
      const int c = cbase + lane;
      GLD16(BT + (size_t)(bn0 + (c >> 2)) * K + k0 + (c & 3) * 8, (char*)Bs + cbase * 16);
    }
    __syncthreads();
    bf16x8 af[MI], bfr[4];
#pragma unroll
    for (int i = 0; i < MI; ++i)
      af[i] = *reinterpret_cast<const bf16x8*>(As + (wr * (MI * 16) + i * 16 + lr) * 32 + lq * 8);
#pragma unroll
    for (int i = 0; i < 4; ++i)
      bfr[i] = *reinterpret_cast<const bf16x8*>(Bs + (wc * 64 + i * 16 + lr) * 32 + lq * 8);
#pragma unroll
    for (int mi = 0; mi < MI; ++mi)
#pragma unroll
      for (int ni = 0; ni < 4; ++ni)
        acc[mi][ni] = __builtin_amdgcn_mfma_f32_16x16x32_bf16(af[mi], bfr[ni], acc[mi][ni], 0, 0, 0);
    __syncthreads();
  }

#pragma unroll
  for (int mi = 0; mi < MI; ++mi) {
#pragma unroll
    for (int ni = 0; ni < 4; ++ni) {
      const int col = bn0 + wc * 64 + ni * 16 + lr;
      const float bv = (EPI >= 1) ? bias[col] : 0.0f;
#pragma unroll
      for (int j = 0; j < 4; ++j) {
        const int row = bm0 + wr * (MI * 16) + mi * 16 + lq * 4 + j;
        float v = acc[mi][ni][j] + bv;
        if (HASRES) v += RES[(size_t)row * N + col];
        if (EPI == 2) v = 0.5f * v * (1.0f + erff(v * 0.70710678118654752f));
        if (OUTB) Cb[(size_t)row * N + col] = __float2bfloat16(v);
        else      Cf[(size_t)row * N + col] = v;
      }
    }
  }
}

// ---------------- causal flash attention v5 ----------------
// Block: 32 q-rows, 4 waves split-K round-robin (KVBLK=32), no in-loop barriers.
// Swapped QK (lane owns one q-row); K prefetched in regs one tile ahead;
// V staged ROW-major per wave via global_load_lds (async DMA, conflict-free);
// PV A-frags (V^T) assembled via scalar ds_read_u16 (2-way, free). O^T partials
// merged across waves at the end.

#define DIAG_MASK(sv)                                                               \
  _Pragma("unroll")                                                                 \
  for (int r = 0; r < 16; ++r) {                                                    \
    const int kl = (r & 3) + 8 * (r >> 2) + 4 * hi;                                 \
    if (kl > lq32) sv[r] = -1e30f;                                                  \
  }

#define PV_HALF(wl0, wl1, wh0, wh1, ksg)                                            \
  {                                                                                 \
    unsigned t0_ = hi ? (wl0) : (wh0);                                              \
    unsigned t1_ = hi ? (wl1) : (wh1);                                              \
    t0_ = (unsigned)__shfl_xor((int)t0_, 32);                                       \
    t1_ = (unsigned)__shfl_xor((int)t1_, 32);                                       \
    u32x4 fw;                                                                       \
    fw[0] = hi ? t0_ : (wl0);  fw[1] = hi ? t1_ : (wl1);                            \
    fw[2] = hi ? (wh0) : t0_;  fw[3] = hi ? (wh1) : t1_;                            \
    bf16x8 pfb = __builtin_bit_cast(bf16x8, fw);                                    \
    const int krow_ = (ksg) * 16 + 8 * hi;                                          \
    bf16x8 vA, vB;                                                                  \
    _Pragma("unroll")                                                               \
    for (int j_ = 0; j_ < 8; ++j_) {                                                \
      vA[j_] = VwB[(krow_ + j_) * 64 + lq32];                                       \
      vB[j_] = VwB[(krow_ + j_) * 64 + 32 + lq32];                                  \
    }                                                                               \
    __builtin_amdgcn_s_setprio(1);                                                  \
    o0 = __builtin_amdgcn_mfma_f32_32x32x16_bf16(vA, pfb, o0, 0, 0, 0);             \
    o1 = __builtin_amdgcn_mfma_f32_32x32x16_bf16(vB, pfb, o1, 0, 0, 0);             \
    __builtin_amdgcn_s_setprio(0);                                                  \
  }

__global__ __launch_bounds__(256, 4) void attn_k(const __hip_bfloat16* __restrict__ qkv,
                                                 __hip_bfloat16* __restrict__ outb) {
  __shared__ __align__(16) char smem[4 * 8192 + 2048];
  // XCD-aware swizzle: xcd = bid%8 owns 4 heads; heavy q-blocks dispatched first
  const int bid = blockIdx.x;
  const int seq = bid >> 3;
  const int bh  = (bid & 7) * 4 + (seq & 3);     // 0..31
  const int qt32 = 63 - (seq >> 2);              // 0..63, heavy first
  const int b = bh >> 4, h = bh & 15;
  const int qb = qt32 * 32;
  const int tid = threadIdx.x;
  const int lane = tid & 63, wave = tid >> 6;
  const int lq32 = lane & 31, hi = lane >> 5;
  const size_t rowbase = (size_t)(b * L_SEQ) * QKV_LD;
  char* const Vw = smem + wave * 8192;           // wave slice: V rows (4KB) / O^T partials (8KB)
  const __bf16* const VwB = (const __bf16*)Vw;
  float* const ML = (float*)(smem + 32768);

  // Q B-frags: lane holds Q[qb+lq32][16c + 8hi + j]
  bf16x8 qf[4];
  {
    const __hip_bfloat16* qp = qkv + rowbase + (size_t)(qb + lq32) * QKV_LD + h * HDIM + 8 * hi;
#pragma unroll
    for (int c = 0; c < 4; ++c) qf[c] = *reinterpret_cast<const bf16x8*>(qp + 16 * c);
  }

  f32x16 o0 = {}, o1 = {};
  float m = -1e30f, lsum = 0.0f;

  int t = wave;
  bf16x8 kr0, kr1, kr2, kr3;
  if (t <= qt32) {                               // prime K regs for first tile
    const __hip_bfloat16* kp = qkv + rowbase + (size_t)(t * 32 + lq32) * QKV_LD + DM + h * HDIM + 8 * hi;
    kr0 = *reinterpret_cast<const bf16x8*>(kp);
    kr1 = *reinterpret_cast<const bf16x8*>(kp + 16);
    kr2 = *reinterpret_cast<const bf16x8*>(kp + 32);
    kr3 = *reinterpret_cast<const bf16x8*>(kp + 48);
  }

  for (; t <= qt32; t += 4) {
    const int k0 = t * 32;
    const bool pf = (t + 4 <= qt32);
    // ---- prefetch next K tile into regs (consumed next iter) ----
    bf16x8 kn0, kn1, kn2, kn3;
    if (pf) {
      const __hip_bfloat16* kp = qkv + rowbase + (size_t)(k0 + 128 + lq32) * QKV_LD + DM + h * HDIM + 8 * hi;
      kn0 = *reinterpret_cast<const bf16x8*>(kp);
      kn1 = *reinterpret_cast<const bf16x8*>(kp + 16);
      kn2 = *reinterpret_cast<const bf16x8*>(kp + 32);
      kn3 = *reinterpret_cast<const bf16x8*>(kp + 48);
    }
    // ---- V rows -> wave-private LDS via async DMA (linear, conflict-free) ----
#pragma unroll
    for (int p = 0; p < 4; ++p)
      GLD16(qkv + rowbase + (size_t)(k0 + 8 * p + (lane >> 3)) * QKV_LD + 2 * DM + h * HDIM + (lane & 7) * 8,
            Vw + p * 1024);
    // ---- QK ----
    f32x16 s = {};
    __builtin_amdgcn_s_setprio(1);
    s = __builtin_amdgcn_mfma_f32_32x32x16_bf16(kr0, qf[0], s, 0, 0, 0);
    s = __builtin_amdgcn_mfma_f32_32x32x16_bf16(kr1, qf[1], s, 0, 0, 0);
    s = __builtin_amdgcn_mfma_f32_32x32x16_bf16(kr2, qf[2], s, 0, 0, 0);
    s = __builtin_amdgcn_mfma_f32_32x32x16_bf16(kr3, qf[3], s, 0, 0, 0);
    __builtin_amdgcn_s_setprio(0);
    if (t == qt32) { DIAG_MASK(s) }
    // ---- online softmax (tree max, defer-rescale THR) ----
    float a0 = fmaxf(s[0], s[1]),   a1 = fmaxf(s[2], s[3]);
    float a2 = fmaxf(s[4], s[5]),   a3 = fmaxf(s[6], s[7]);
    float a4 = fmaxf(s[8], s[9]),   a5 = fmaxf(s[10], s[11]);
    float a6 = fmaxf(s[12], s[13]), a7 = fmaxf(s[14], s[15]);
    a0 = fmaxf(a0, a1); a2 = fmaxf(a2, a3); a4 = fmaxf(a4, a5); a6 = fmaxf(a6, a7);
    float tm = fmaxf(fmaxf(a0, a2), fmaxf(a4, a6));
    tm = fmaxf(tm, __shfl_xor(tm, 32));
    if (!__all(tm <= m + DTHR)) {
      const float mn = fmaxf(m, tm);
      const float fac = __builtin_amdgcn_exp2f((m - mn) * RL);
      m = mn; lsum *= fac; o0 *= fac; o1 *= fac;
    }
    const float mneg = -m * RL;
    float rs = 0.0f;
#pragma unroll
    for (int r = 0; r < 16; ++r) {
      s[r] = __builtin_amdgcn_exp2f(fmaf(s[r], RL, mneg));
      rs += s[r];
    }
    rs += __shfl_xor(rs, 32);
    lsum += rs;
    // ---- PV ----
    unsigned w0 = pack2(s[0], s[1]),   w1 = pack2(s[2], s[3]);
    unsigned w2 = pack2(s[4], s[5]),   w3 = pack2(s[6], s[7]);
    unsigned w4 = pack2(s[8], s[9]),   w5 = pack2(s[10], s[11]);
    unsigned w6 = pack2(s[12], s[13]), w7 = pack2(s[14], s[15]);
    PV_HALF(w0, w1, w2, w3, 0)
    PV_HALF(w4, w5, w6, w7, 1)
    if (pf) { kr0 = kn0; kr1 = kn1; kr2 = kn2; kr3 = kn3; }
  }

  // ---- write partials (O^T into own slice; m,l) ----
  {
    float* Ow = (float*)Vw;
#pragma unroll
    for (int r = 0; r < 16; ++r) {
      const int d0 = (r & 3) + 8 * (r >> 2) + 4 * hi;
      Ow[d0 * 32 + lq32] = o0[r];
      Ow[(d0 + 32) * 32 + lq32] = o1[r];
    }
    if (hi == 0) {
      ML[wave * 128 + lq32] = m;
      ML[wave * 128 + 64 + lq32] = lsum;
    }
  }
  __syncthreads();

  // ---- combine 4 partials; each thread: one q (tid&31), 8 d's ----
  {
    const int q = tid & 31, dg = tid >> 5;    // dg 0..7
    const float m0 = ML[q], m1 = ML[128 + q], m2 = ML[256 + q], m3 = ML[384 + q];
    const float M = fmaxf(fmaxf(m0, m1), fmaxf(m2, m3));
    const float c0 = __builtin_amdgcn_exp2f((m0 - M) * RL);
    const float c1 = __builtin_amdgcn_exp2f((m1 - M) * RL);
    const float c2 = __builtin_amdgcn_exp2f((m2 - M) * RL);
    const float c3 = __builtin_amdgcn_exp2f((m3 - M) * RL);
    const float l = c0 * ML[64 + q] + c1 * ML[192 + q] + c2 * ML[320 + q] + c3 * ML[448 + q];
    const float inv = 1.0f / l;
    const float* OB = (const float*)smem;
    bf16x8 ov;
#pragma unroll
    for (int i = 0; i < 8; ++i) {
      const int idx = (dg * 8 + i) * 32 + q;
      const float v = c0 * OB[idx] + c1 * OB[2048 + idx] + c2 * OB[4096 + idx] + c3 * OB[6144 + idx];
      ov[i] = (__bf16)(v * inv);
    }
    *reinterpret_cast<bf16x8*>(outb + (size_t)(b * L_SEQ + qb + q) * DM + h * HDIM + dg * 8) = ov;
  }
}

// ---------------- LayerNorm: Y = LN(X) * g + be (X already has residual) ----------------
template<int WB>
__global__ __launch_bounds__(256) void ln_k(const float* __restrict__ X,
                                            const float* __restrict__ g,
                                            const float* __restrict__ be,
                                            float* __restrict__ Y,
                                            __hip_bfloat16* __restrict__ Yb) {
  const int row = blockIdx.x;
  const int tid = threadIdx.x;
  const int lane = tid & 63, wave = tid >> 6;
  float4 x4 = *reinterpret_cast<const float4*>(X + (size_t)row * DM + tid * 4);
  float v0 = x4.x, v1 = x4.y, v2 = x4.z, v3 = x4.w;
  float s  = v0 + v1 + v2 + v3;
  float ss = v0 * v0 + v1 * v1 + v2 * v2 + v3 * v3;
#pragma unroll
  for (int off = 1; off < 64; off <<= 1) {
    s  += __shfl_xor(s, off);
    ss += __shfl_xor(ss, off);
  }
  __shared__ float red[8];
  if (lane == 0) { red[wave] = s; red[4 + wave] = ss; }
  __syncthreads();
  float S  = red[0] + red[1] + red[2] + red[3];
  float SS = red[4] + red[5] + red[6] + red[7];
  float mu  = S * (1.0f / DM);
  float var = SS * (1.0f / DM) - mu * mu;
  float rsd = rsqrtf(var + 1e-5f);
  float4 gv = *reinterpret_cast<const float4*>(g + tid * 4);
  float4 bv = *reinterpret_cast<const float4*>(be + tid * 4);
  float4 y;
  y.x = (v0 - mu) * rsd * gv.x + bv.x;
  y.y = (v1 - mu) * rsd * gv.y + bv.y;
  y.z = (v2 - mu) * rsd * gv.z + bv.z;
  y.w = (v3 - mu) * rsd * gv.w + bv.w;
  *reinterpret_cast<float4*>(Y + (size_t)row * DM + tid * 4) = y;
  if (WB) {
    bf16x4 yb;
    yb[0] = (__bf16)y.x; yb[1] = (__bf16)y.y; yb[2] = (__bf16)y.z; yb[3] = (__bf16)y.w;
    *reinterpret_cast<bf16x4*>(Yb + (size_t)row * DM + tid * 4) = yb;
  }
}

extern "C" void kernel_launch(void* const* d_in, const int* in_sizes, int n_in,
                              void* d_out, int out_size, void* d_ws, size_t ws_size,
                              hipStream_t stream) {
  const float* x     = (const float*)d_in[0];
  const float* w_qkv = (const float*)d_in[1];
  const float* w_out = (const float*)d_in[2];
  const float* w1    = (const float*)d_in[3];
  const float* b1    = (const float*)d_in[4];
  const float* w2    = (const float*)d_in[5];
  const float* b2    = (const float*)d_in[6];
  const float* g1    = (const float*)d_in[7];
  const float* be1   = (const float*)d_in[8];
  const float* g2    = (const float*)d_in[9];
  const float* be2   = (const float*)d_in[10];
  float* outp = (float*)d_out;
  char* base  = (char*)d_ws;
  const int M = NB * L_SEQ;                 // 4096

  __hip_bfloat16* w2T  = (__hip_bfloat16*)(base + 0);          // [1024][2048]
  __hip_bfloat16* woT  = (__hip_bfloat16*)(base + 4194304);    // [1024][1024]
  __hip_bfloat16* w1T  = (__hip_bfloat16*)(base + 6291456);    // [2048][1024]
  __hip_bfloat16* wqT  = (__hip_bfloat16*)(base + 10485760);   // [3072][1024]
  __hip_bfloat16* xb   = (__hip_bfloat16*)(base + 16777216);   // [4096][1024]
  __hip_bfloat16* attnb= xb;                                   // reuse after qkv GEMM
  __hip_bfloat16* qkvb = (__hip_bfloat16*)(base + 25165824);   // [4096][3072]
  __hip_bfloat16* ffh  = (__hip_bfloat16*)(base + 25165824);   // [4096][2048] (qkvb dead)
  __hip_bfloat16* ln1b = (__hip_bfloat16*)(base + 41943040);   // [4096][1024] (qkvb dead)
  float*          ffo  = (float*)(base + 8388608);             // [4096][1024] f32
  float*          ln1f = (float*)(base + 50331648);            // [4096][1024] f32
  float*          proj = outp;                                 // d_out as scratch

  // fused prep: all weight transposes + x convert
  prep_k<<<10240, 256, 0, stream>>>(w_qkv, w_out, w1, w2, x, wqT, woT, w1T, w2T, xb);

  // 1. qkv = x @ w_qkv (bf16)
  gemm2<0, 1, 0, 128><<<dim3(24, 32), 256, 0, stream>>>(xb, wqT, nullptr, nullptr, qkvb, nullptr, M, QKV_LD, DM);
  // 2. attention (bf16): 64 q-blocks x 32 bh, XCD-swizzled
  attn_k<<<2048, 256, 0, stream>>>(qkvb, attnb);
  // 3. proj = attn @ w_out + x  (f32, residual fused; BN=64 -> 512 blocks)
  gemm2<0, 0, 1, 64><<<dim3(16, 32), 256, 0, stream>>>(attnb, woT, nullptr, proj, nullptr, x, M, DM, DM);
  // 4. ln1 = LN(proj)
  ln_k<1><<<M, 256, 0, stream>>>(proj, g1, be1, ln1f, ln1b);
  // 5. ffh = gelu(ln1 @ w1 + b1) (bf16)
  gemm2<2, 1, 0, 128><<<dim3(16, 32), 256, 0, stream>>>(ln1b, w1T, b1, nullptr, ffh, nullptr, M, 2 * DM, DM);
  // 6. ffo = ffh @ w2 + b2 + ln1 (f32, residual fused; BN=64)
  gemm2<1, 0, 1, 64><<<dim3(16, 32), 256, 0, stream>>>(ffh, w2T, b2, ffo, nullptr, ln1f, M, DM, 2 * DM);
  // 7. out = LN(ffo)
  ln_k<0><<<M, 256, 0, stream>>>(ffo, g2, be2, outp, nullptr);
}

// Round 8
// 221.626 us; speedup vs baseline: 2.9311x; 1.0003x over previous
//
#include <hip/hip_runtime.h>
#include <hip/hip_bf16.h>
#include <math.h>

#define L_SEQ 2048
#define NB 2
#define DM 1024
#define NHEAD 16
#define HDIM 64
#define QKV_LD 3072
#define RL 0.18033688011112042f   // 0.125 * log2(e)
#define DTHR 44.3614f             // 8 / RL  (defer-max threshold in raw score units)
#define VSTRIDE 72                // V^T row stride in bytes (18 dw -> distinct banks)
#define VBUF 4608                 // 64 * 72
#define WSLICE 9216               // 2 * VBUF per wave
#define WSLICE_F 2304             // WSLICE / 4 (floats)

typedef __attribute__((ext_vector_type(8))) __bf16 bf16x8;
typedef __attribute__((ext_vector_type(4))) __bf16 bf16x4;
typedef __attribute__((ext_vector_type(4))) float f32x4;
typedef __attribute__((ext_vector_type(16))) float f32x16;
typedef __attribute__((ext_vector_type(8))) unsigned short u16x8;
typedef __attribute__((ext_vector_type(4))) unsigned int u32x4;

typedef __attribute__((address_space(3))) unsigned int lds_u32;
typedef const __attribute__((address_space(1))) unsigned int glob_u32;
#define GLD16(g, l) __builtin_amdgcn_global_load_lds((glob_u32*)(g), (lds_u32*)(l), 16, 0, 0)

__device__ __forceinline__ unsigned pack2(float a, float b) {
  unsigned short ua = __builtin_bit_cast(unsigned short, (__bf16)a);
  unsigned short ub = __builtin_bit_cast(unsigned short, (__bf16)b);
  return (unsigned)ua | ((unsigned)ub << 16);
}

// ---------------- fused prep: 4 weight transposes + x convert ----------------
__global__ __launch_bounds__(256) void prep_k(const float* __restrict__ w_qkv,
                                              const float* __restrict__ w_out,
                                              const float* __restrict__ w1,
                                              const float* __restrict__ w2,
                                              const float* __restrict__ x,
                                              __hip_bfloat16* __restrict__ wqT,
                                              __hip_bfloat16* __restrict__ woT,
                                              __hip_bfloat16* __restrict__ w1T,
                                              __hip_bfloat16* __restrict__ w2T,
                                              __hip_bfloat16* __restrict__ xb) {
  const int id = blockIdx.x;
  if (id >= 8192) {                     // x f32 -> bf16
    const size_t base = ((size_t)(id - 8192) * 256 + threadIdx.x) * 8;
    float4 a = *reinterpret_cast<const float4*>(x + base);
    float4 b = *reinterpret_cast<const float4*>(x + base + 4);
    bf16x8 o;
    o[0] = (__bf16)a.x; o[1] = (__bf16)a.y; o[2] = (__bf16)a.z; o[3] = (__bf16)a.w;
    o[4] = (__bf16)b.x; o[5] = (__bf16)b.y; o[6] = (__bf16)b.z; o[7] = (__bf16)b.w;
    *reinterpret_cast<bf16x8*>(xb + base) = o;
    return;
  }
  const float* W; __hip_bfloat16* WT; int K, N, kb, nb;
  if (id < 3072)      { W = w_qkv; WT = wqT; K = 1024; N = 3072; kb = id & 31;          nb = id >> 5; }
  else if (id < 4096) { W = w_out; WT = woT; K = 1024; N = 1024; kb = (id - 3072) & 31; nb = (id - 3072) >> 5; }
  else if (id < 6144) { W = w1;    WT = w1T; K = 1024; N = 2048; kb = (id - 4096) & 31; nb = (id - 4096) >> 5; }
  else                { W = w2;    WT = w2T; K = 2048; N = 1024; kb = (id - 6144) & 63; nb = (id - 6144) >> 6; }
  __shared__ float tsm[32][33];
  const int k0 = kb * 32, n0 = nb * 32;
  const int c = threadIdx.x & 31, r = threadIdx.x >> 5;
#pragma unroll
  for (int i = 0; i < 4; ++i)
    tsm[r + 8 * i][c] = W[(size_t)(k0 + r + 8 * i) * N + n0 + c];
  __syncthreads();
#pragma unroll
  for (int i = 0; i < 4; ++i)
    WT[(size_t)(n0 + r + 8 * i) * K + k0 + c] = __float2bfloat16(tsm[c][r + 8 * i]);
}

// ---------------- GEMM (m97 structure): C = A[M,K] @ BT[N,K]^T ----------------
// EPI: 0 none, 1 +bias, 2 +bias+gelu. OUTB: bf16/f32. HASRES: 0 none, 1 f32, 2 bf16. BN: 128/64.
template<int EPI, int OUTB, int HASRES, int BN>
__global__ __launch_bounds__(256) void gemm2(const __hip_bfloat16* __restrict__ A,
                                             const __hip_bfloat16* __restrict__ BT,
                                             const float* __restrict__ bias,
                                             float* __restrict__ Cf,
                                             __hip_bfloat16* __restrict__ Cb,
                                             const float* __restrict__ RESF,
                                             const __hip_bfloat16* __restrict__ RESB,
                                             int M, int N, int K) {
  constexpr int MI = (BN == 128) ? 4 : 2;
  __shared__ __align__(16) __hip_bfloat16 As[128 * 32];
  __shared__ __align__(16) __hip_bfloat16 Bs[BN * 32];
  const int tid  = threadIdx.x;
  const int lane = tid & 63, wave = tid >> 6;
  const int wr = (BN == 128) ? (wave >> 1) : wave;
  const int wc = (BN == 128) ? (wave & 1) : 0;
  const int lr = lane & 15, lq = lane >> 4;
  const int bm0 = blockIdx.y * 128, bn0 = blockIdx.x * BN;
  f32x4 acc[MI][4] = {};

  for (int k0 = 0; k0 < K; k0 += 32) {
#pragma unroll
    for (int j = 0; j < 2; ++j) {
      const int cbase = j * 256 + wave * 64;
      const int c = cbase + lane;
      GLD16(A + (size_t)(bm0 + (c >> 2)) * K + k0 + (c & 3) * 8, (char*)As + cbase * 16);
    }
#pragma unroll
    for (int j = 0; j < BN / 64; ++j) {
      const int cbase = j * 256 + wave * 64;
      const int c = cbase + lane;
      GLD16(BT + (size_t)(bn0 + (c >> 2)) * K + k0 + (c & 3) * 8, (char*)Bs + cbase * 16);
    }
    __syncthreads();
    bf16x8 af[MI], bfr[4];
#pragma unroll
    for (int i = 0; i < MI; ++i)
      af[i] = *reinterpret_cast<const bf16x8*>(As + (wr * (MI * 16) + i * 16 + lr) * 32 + lq * 8);
#pragma unroll
    for (int i = 0; i < 4; ++i)
      bfr[i] = *reinterpret_cast<const bf16x8*>(Bs + (wc * 64 + i * 16 + lr) * 32 + lq * 8);
#pragma unroll
    for (int mi = 0; mi < MI; ++mi)
#pragma unroll
      for (int ni = 0; ni < 4; ++ni)
        acc[mi][ni] = __builtin_amdgcn_mfma_f32_16x16x32_bf16(af[mi], bfr[ni], acc[mi][ni], 0, 0, 0);
    __syncthreads();
  }

#pragma unroll
  for (int mi = 0; mi < MI; ++mi) {
#pragma unroll
    for (int ni = 0; ni < 4; ++ni) {
      const int col = bn0 + wc * 64 + ni * 16 + lr;
      const float bv = (EPI >= 1) ? bias[col] : 0.0f;
#pragma unroll
      for (int j = 0; j < 4; ++j) {
        const int row = bm0 + wr * (MI * 16) + mi * 16 + lq * 4 + j;
        float v = acc[mi][ni][j] + bv;
        if (HASRES == 1) v += RESF[(size_t)row * N + col];
        if (HASRES == 2) v += __bfloat162float(RESB[(size_t)row * N + col]);
        if (EPI == 2) v = 0.5f * v * (1.0f + erff(v * 0.70710678118654752f));
        if (OUTB) Cb[(size_t)row * N + col] = __float2bfloat16(v);
        else      Cf[(size_t)row * N + col] = v;
      }
    }
  }
}

// ---------------- causal flash attention v7: V^T stride-72 LDS ----------------
// Block: 32 q-rows, 4 waves split-K round-robin (KVBLK=32), no in-loop barriers.
// Swapped QK (lane owns one q-row). V staged TRANSPOSED in wave-private LDS with
// 72B row stride (16 distinct start banks for both the uint writes and the b64
// PV reads), double-buffered (stage t+4 while computing t). K loaded at loop top
// (TLP covers L2 latency). O^T partials merged once at the end.

#define DIAG_MASK(sv)                                                               \
  _Pragma("unroll")                                                                 \
  for (int r = 0; r < 16; ++r) {                                                    \
    const int kl = (r & 3) + 8 * (r >> 2) + 4 * hi;                                 \
    if (kl > lq32) sv[r] = -1e30f;                                                  \
  }

// stage one 32-key V tile, transposed, into buffer sel_: V^T[d][key] @ d*72+key*2
#define V_STAGE(t_, sel_)                                                           \
  _Pragma("unroll")                                                                 \
  for (int c_ = 0; c_ < 2; ++c_) {                                                  \
    const __hip_bfloat16* vp_ = qkv + rowbase                                       \
        + (size_t)((t_) * 32 + 4 * kp + 2 * c_) * QKV_LD + 2 * DM + h * HDIM + d8 * 8; \
    u16x8 lo_ = *reinterpret_cast<const u16x8*>(vp_);                               \
    u16x8 hi_ = *reinterpret_cast<const u16x8*>(vp_ + QKV_LD);                      \
    _Pragma("unroll")                                                               \
    for (int i_ = 0; i_ < 8; ++i_) {                                                \
      const int d_ = d8 * 8 + i_;                                                   \
      *reinterpret_cast<unsigned*>(Vw + (sel_) * VBUF + d_ * VSTRIDE                \
                                   + (4 * kp + 2 * c_) * 2) =                       \
          (unsigned)lo_[i_] | ((unsigned)hi_[i_] << 16);                            \
    }                                                                               \
  }

#define K_LOAD(t_, r0, r1, r2, r3)                                                  \
  { const __hip_bfloat16* kp_ = qkv + rowbase + (size_t)((t_) * 32 + lq32) * QKV_LD \
                                + DM + h * HDIM + 8 * hi;                           \
    r0 = *reinterpret_cast<const bf16x8*>(kp_);                                     \
    r1 = *reinterpret_cast<const bf16x8*>(kp_ + 16);                                \
    r2 = *reinterpret_cast<const bf16x8*>(kp_ + 32);                                \
    r3 = *reinterpret_cast<const bf16x8*>(kp_ + 48); }

#define MK_PF(pf_, wl0, wl1, wh0, wh1)                                              \
  bf16x8 pf_;                                                                       \
  { unsigned t0_ = hi ? (wl0) : (wh0);                                              \
    unsigned t1_ = hi ? (wl1) : (wh1);                                              \
    t0_ = (unsigned)__shfl_xor((int)t0_, 32);                                       \
    t1_ = (unsigned)__shfl_xor((int)t1_, 32);                                       \
    u32x4 fw_;                                                                      \
    fw_[0] = hi ? t0_ : (wl0);  fw_[1] = hi ? t1_ : (wl1);                          \
    fw_[2] = hi ? (wh0) : t0_;  fw_[3] = hi ? (wh1) : t1_;                          \
    pf_ = __builtin_bit_cast(bf16x8, fw_); }

// PV fragment reads: vA[j]=V^T[lq32][16ksg+8hi+j], vB[j]=V^T[32+lq32][...]
#define PV_READS(ksg_, bb_, vA_, vB_)                                               \
  bf16x8 vA_, vB_;                                                                  \
  { const char* pa_ = (bb_) + lq32 * VSTRIDE + 32 * (ksg_) + 16 * hi;               \
    uint2 a0_ = *reinterpret_cast<const uint2*>(pa_);                               \
    uint2 a1_ = *reinterpret_cast<const uint2*>(pa_ + 8);                           \
    const char* pb_ = (bb_) + (32 + lq32) * VSTRIDE + 32 * (ksg_) + 16 * hi;        \
    uint2 b0_ = *reinterpret_cast<const uint2*>(pb_);                               \
    uint2 b1_ = *reinterpret_cast<const uint2*>(pb_ + 8);                           \
    vA_ = __builtin_bit_cast(bf16x8, (u32x4){a0_.x, a0_.y, a1_.x, a1_.y});          \
    vB_ = __builtin_bit_cast(bf16x8, (u32x4){b0_.x, b0_.y, b1_.x, b1_.y}); }

__global__ __launch_bounds__(256) void attn_k(const __hip_bfloat16* __restrict__ qkv,
                                              __hip_bfloat16* __restrict__ outb) {
  __shared__ __align__(16) char smem[4 * WSLICE + 2048];
  const int bid = blockIdx.x;
  const int seq = bid >> 3;
  const int bh  = (bid & 7) * 4 + (seq & 3);     // xcd-affine head grouping
  const int qt32 = 63 - (seq >> 2);              // heavy q-blocks first
  const int b = bh >> 4, h = bh & 15;
  const int qb = qt32 * 32;
  const int tid = threadIdx.x;
  const int lane = tid & 63, wave = tid >> 6;
  const int lq32 = lane & 31, hi = lane >> 5;
  const int kp = lane >> 3, d8 = lane & 7;       // V staging coords
  const size_t rowbase = (size_t)(b * L_SEQ) * QKV_LD;
  char* const Vw = smem + wave * WSLICE;         // 2 V^T buffers; O^T partials after loop
  float* const ML = (float*)(smem + 4 * WSLICE);

  // Q B-frags: lane holds Q[qb+lq32][16c + 8hi + j]
  bf16x8 qf[4];
  {
    const __hip_bfloat16* qp = qkv + rowbase + (size_t)(qb + lq32) * QKV_LD + h * HDIM + 8 * hi;
#pragma unroll
    for (int c = 0; c < 4; ++c) qf[c] = *reinterpret_cast<const bf16x8*>(qp + 16 * c);
  }

  f32x16 o0 = {}, o1 = {};
  float m = -1e30f, lsum = 0.0f;

  int t = wave;
  unsigned sel = 0;
  if (t <= qt32) { V_STAGE(t, 0) }               // prologue: stage first V tile

  for (; t <= qt32; t += 4) {
    // ---- K loads for current tile issue FIRST (in flight during V staging) ----
    bf16x8 kr0, kr1, kr2, kr3;
    K_LOAD(t, kr0, kr1, kr2, kr3)
    // ---- stage NEXT V tile into other buffer (load waits overlap K flight) ----
    const bool pf = (t + 4 <= qt32);
    if (pf) { V_STAGE(t + 4, sel ^ 1) }
    // ---- QK ----
    f32x16 s = {};
    __builtin_amdgcn_s_setprio(1);
    s = __builtin_amdgcn_mfma_f32_32x32x16_bf16(kr0, qf[0], s, 0, 0, 0);
    s = __builtin_amdgcn_mfma_f32_32x32x16_bf16(kr1, qf[1], s, 0, 0, 0);
    s = __builtin_amdgcn_mfma_f32_32x32x16_bf16(kr2, qf[2], s, 0, 0, 0);
    s = __builtin_amdgcn_mfma_f32_32x32x16_bf16(kr3, qf[3], s, 0, 0, 0);
    __builtin_amdgcn_s_setprio(0);
    if (t == qt32) { DIAG_MASK(s) }
    // ---- max + deferred rescale ----
    float a0 = fmaxf(s[0], s[1]),   a1 = fmaxf(s[2], s[3]);
    float a2 = fmaxf(s[4], s[5]),   a3 = fmaxf(s[6], s[7]);
    float a4 = fmaxf(s[8], s[9]),   a5 = fmaxf(s[10], s[11]);
    float a6 = fmaxf(s[12], s[13]), a7 = fmaxf(s[14], s[15]);
    a0 = fmaxf(a0, a1); a2 = fmaxf(a2, a3); a4 = fmaxf(a4, a5); a6 = fmaxf(a6, a7);
    float tm = fmaxf(fmaxf(a0, a2), fmaxf(a4, a6));
    tm = fmaxf(tm, __shfl_xor(tm, 32));
    if (!__all(tm <= m + DTHR)) {
      const float mn = fmaxf(m, tm);
      const float fac = __builtin_amdgcn_exp2f((m - mn) * RL);
      m = mn; lsum *= fac; o0 *= fac; o1 *= fac;
    }
    // ---- exp + sum ----
    const float mneg = -m * RL;
    float rs = 0.0f;
#pragma unroll
    for (int r = 0; r < 16; ++r) {
      s[r] = __builtin_amdgcn_exp2f(fmaf(s[r], RL, mneg));
      rs += s[r];
    }
    rs += __shfl_xor(rs, 32);
    lsum += rs;
    // ---- P pack + cross-half exchange ----
    unsigned w0 = pack2(s[0], s[1]),   w1 = pack2(s[2], s[3]);
    unsigned w2 = pack2(s[4], s[5]),   w3 = pack2(s[6], s[7]);
    unsigned w4 = pack2(s[8], s[9]),   w5 = pack2(s[10], s[11]);
    unsigned w6 = pack2(s[12], s[13]), w7 = pack2(s[14], s[15]);
    MK_PF(pf0, w0, w1, w2, w3)
    MK_PF(pf1, w4, w5, w6, w7)
    // ---- PV: 8 b64 reads from current V^T buffer ----
    const char* vb = Vw + sel * VBUF;
    PV_READS(0, vb, vA0, vB0)
    PV_READS(1, vb, vA1, vB1)
    __builtin_amdgcn_s_setprio(1);
    o0 = __builtin_amdgcn_mfma_f32_32x32x16_bf16(vA0, pf0, o0, 0, 0, 0);
    o1 = __builtin_amdgcn_mfma_f32_32x32x16_bf16(vB0, pf0, o1, 0, 0, 0);
    o0 = __builtin_amdgcn_mfma_f32_32x32x16_bf16(vA1, pf1, o0, 0, 0, 0);
    o1 = __builtin_amdgcn_mfma_f32_32x32x16_bf16(vB1, pf1, o1, 0, 0, 0);
    __builtin_amdgcn_s_setprio(0);
    sel ^= 1;
  }

  // ---- write partials (O^T into own wave slice; m,l) ----
  {
    float* Ow = (float*)Vw;
#pragma unroll
    for (int r = 0; r < 16; ++r) {
      const int d0 = (r & 3) + 8 * (r >> 2) + 4 * hi;
      Ow[d0 * 32 + lq32] = o0[r];
      Ow[(d0 + 32) * 32 + lq32] = o1[r];
    }
    if (hi == 0) {
      ML[wave * 128 + lq32] = m;
      ML[wave * 128 + 64 + lq32] = lsum;
    }
  }
  __syncthreads();

  // ---- combine 4 partials; each thread: one q (tid&31), 8 d's ----
  {
    const int q = tid & 31, dg = tid >> 5;
    const float m0 = ML[q], m1 = ML[128 + q], m2 = ML[256 + q], m3 = ML[384 + q];
    const float M = fmaxf(fmaxf(m0, m1), fmaxf(m2, m3));
    const float c0 = __builtin_amdgcn_exp2f((m0 - M) * RL);
    const float c1 = __builtin_amdgcn_exp2f((m1 - M) * RL);
    const float c2 = __builtin_amdgcn_exp2f((m2 - M) * RL);
    const float c3 = __builtin_amdgcn_exp2f((m3 - M) * RL);
    const float l = c0 * ML[64 + q] + c1 * ML[192 + q] + c2 * ML[320 + q] + c3 * ML[448 + q];
    const float inv = 1.0f / l;
    const float* OB = (const float*)smem;
    bf16x8 ov;
#pragma unroll
    for (int i = 0; i < 8; ++i) {
      const int idx = (dg * 8 + i) * 32 + q;
      const float v = c0 * OB[idx] + c1 * OB[WSLICE_F + idx]
                    + c2 * OB[2 * WSLICE_F + idx] + c3 * OB[3 * WSLICE_F + idx];
      ov[i] = (__bf16)(v * inv);
    }
    *reinterpret_cast<bf16x8*>(outb + (size_t)(b * L_SEQ + qb + q) * DM + h * HDIM + dg * 8) = ov;
  }
}

// ---------------- LayerNorm: Y = LN(X) * g + be. MODE 0: f32 out, 2: bf16 out only ----
template<int MODE>
__global__ __launch_bounds__(256) void ln_k(const float* __restrict__ X,
                                            const float* __restrict__ g,
                                            const float* __restrict__ be,
                                            float* __restrict__ Y,
                                            __hip_bfloat16* __restrict__ Yb) {
  const int row = blockIdx.x;
  const int tid = threadIdx.x;
  const int lane = tid & 63, wave = tid >> 6;
  float4 x4 = *reinterpret_cast<const float4*>(X + (size_t)row * DM + tid * 4);
  float v0 = x4.x, v1 = x4.y, v2 = x4.z, v3 = x4.w;
  float s  = v0 + v1 + v2 + v3;
  float ss = v0 * v0 + v1 * v1 + v2 * v2 + v3 * v3;
#pragma unroll
  for (int off = 1; off < 64; off <<= 1) {
    s  += __shfl_xor(s, off);
    ss += __shfl_xor(ss, off);
  }
  __shared__ float red[8];
  if (lane == 0) { red[wave] = s; red[4 + wave] = ss; }
  __syncthreads();
  float S  = red[0] + red[1] + red[2] + red[3];
  float SS = red[4] + red[5] + red[6] + red[7];
  float mu  = S * (1.0f / DM);
  float var = SS * (1.0f / DM) - mu * mu;
  float rsd = rsqrtf(var + 1e-5f);
  float4 gv = *reinterpret_cast<const float4*>(g + tid * 4);
  float4 bv = *reinterpret_cast<const float4*>(be + tid * 4);
  float4 y;
  y.x = (v0 - mu) * rsd * gv.x + bv.x;
  y.y = (v1 - mu) * rsd * gv.y + bv.y;
  y.z = (v2 - mu) * rsd * gv.z + bv.z;
  y.w = (v3 - mu) * rsd * gv.w + bv.w;
  if (MODE != 2)
    *reinterpret_cast<float4*>(Y + (size_t)row * DM + tid * 4) = y;
  if (MODE == 2) {
    bf16x4 yb;
    yb[0] = (__bf16)y.x; yb[1] = (__bf16)y.y; yb[2] = (__bf16)y.z; yb[3] = (__bf16)y.w;
    *reinterpret_cast<bf16x4*>(Yb + (size_t)row * DM + tid * 4) = yb;
  }
}

extern "C" void kernel_launch(void* const* d_in, const int* in_sizes, int n_in,
                              void* d_out, int out_size, void* d_ws, size_t ws_size,
                              hipStream_t stream) {
  const float* x     = (const float*)d_in[0];
  const float* w_qkv = (const float*)d_in[1];
  const float* w_out = (const float*)d_in[2];
  const float* w1    = (const float*)d_in[3];
  const float* b1    = (const float*)d_in[4];
  const float* w2    = (const float*)d_in[5];
  const float* b2    = (const float*)d_in[6];
  const float* g1    = (const float*)d_in[7];
  const float* be1   = (const float*)d_in[8];
  const float* g2    = (const float*)d_in[9];
  const float* be2   = (const float*)d_in[10];
  float* outp = (float*)d_out;
  char* base  = (char*)d_ws;
  const int M = NB * L_SEQ;                 // 4096

  __hip_bfloat16* w2T  = (__hip_bfloat16*)(base + 0);          // [1024][2048]
  __hip_bfloat16* woT  = (__hip_bfloat16*)(base + 4194304);    // [1024][1024]
  __hip_bfloat16* w1T  = (__hip_bfloat16*)(base + 6291456);    // [2048][1024]
  __hip_bfloat16* wqT  = (__hip_bfloat16*)(base + 10485760);   // [3072][1024]
  __hip_bfloat16* xb   = (__hip_bfloat16*)(base + 16777216);   // [4096][1024]
  __hip_bfloat16* attnb= xb;                                   // reuse after qkv GEMM
  __hip_bfloat16* qkvb = (__hip_bfloat16*)(base + 25165824);   // [4096][3072]
  __hip_bfloat16* ffh  = (__hip_bfloat16*)(base + 25165824);   // [4096][2048] (qkvb dead)
  __hip_bfloat16* ln1b = (__hip_bfloat16*)(base + 41943040);   // [4096][1024] (qkvb dead)
  float*          ffo  = (float*)(base + 8388608);             // [4096][1024] f32 (dead wts+xb)
  float*          proj = outp;                                 // d_out as scratch

  // fused prep: all weight transposes + x convert
  prep_k<<<10240, 256, 0, stream>>>(w_qkv, w_out, w1, w2, x, wqT, woT, w1T, w2T, xb);

  // 1. qkv = x @ w_qkv (bf16)
  gemm2<0, 1, 0, 128><<<dim3(24, 32), 256, 0, stream>>>(xb, wqT, nullptr, nullptr, qkvb, nullptr, nullptr, M, QKV_LD, DM);
  // 2. attention (bf16): 64 q-blocks x 32 bh, XCD-swizzled
  attn_k<<<2048, 256, 0, stream>>>(qkvb, attnb);
  // 3. proj = attn @ w_out + x  (f32, residual fused; BN=64)
  gemm2<0, 0, 1, 64><<<dim3(16, 32), 256, 0, stream>>>(attnb, woT, nullptr, proj, nullptr, x, nullptr, M, DM, DM);
  // 4. ln1 = LN(proj)  (bf16 only)
  ln_k<2><<<M, 256, 0, stream>>>(proj, g1, be1, nullptr, ln1b);
  // 5. ffh = gelu(ln1 @ w1 + b1) (bf16)
  gemm2<2, 1, 0, 128><<<dim3(16, 32), 256, 0, stream>>>(ln1b, w1T, b1, nullptr, ffh, nullptr, nullptr, M, 2 * DM, DM);
  // 6. ffo = ffh @ w2 + b2 + ln1 (f32; bf16 residual; BN=64)
  gemm2<1, 0, 2, 64><<<dim3(16, 32), 256, 0, stream>>>(ffh, w2T, b2, ffo, nullptr, nullptr, ln1b, M, DM, 2 * DM);
  // 7. out = LN(ffo)
  ln_k<0><<<M, 256, 0, stream>>>(ffo, g2, be2, outp, nullptr);
}

// Round 9
// 194.620 us; speedup vs baseline: 3.3378x; 1.1388x over previous
//
#include <hip/hip_runtime.h>
#include <hip/hip_bf16.h>
#include <math.h>

#define L_SEQ 2048
#define NB 2
#define DM 1024
#define NHEAD 16
#define HDIM 64
#define QKV_LD 3072
#define RL 0.18033688011112042f   // 0.125 * log2(e)
#define DTHR 44.3614f             // 8 / RL  (defer-max threshold in raw score units)

typedef __attribute__((ext_vector_type(8))) __bf16 bf16x8;
typedef __attribute__((ext_vector_type(4))) __bf16 bf16x4;
typedef __attribute__((ext_vector_type(4))) float f32x4;
typedef __attribute__((ext_vector_type(16))) float f32x16;
typedef __attribute__((ext_vector_type(4))) unsigned int u32x4;

typedef __attribute__((address_space(3))) unsigned int lds_u32;
typedef const __attribute__((address_space(1))) unsigned int glob_u32;
#define GLD16(g, l) __builtin_amdgcn_global_load_lds((glob_u32*)(g), (lds_u32*)(l), 16, 0, 0)

__device__ __forceinline__ unsigned pack2(float a, float b) {
  unsigned short ua = __builtin_bit_cast(unsigned short, (__bf16)a);
  unsigned short ub = __builtin_bit_cast(unsigned short, (__bf16)b);
  return (unsigned)ua | ((unsigned)ub << 16);
}

// ---------------- fused prep: 4 weight transposes + x convert ----------------
__global__ __launch_bounds__(256) void prep_k(const float* __restrict__ w_qkv,
                                              const float* __restrict__ w_out,
                                              const float* __restrict__ w1,
                                              const float* __restrict__ w2,
                                              const float* __restrict__ x,
                                              __hip_bfloat16* __restrict__ wqT,
                                              __hip_bfloat16* __restrict__ woT,
                                              __hip_bfloat16* __restrict__ w1T,
                                              __hip_bfloat16* __restrict__ w2T,
                                              __hip_bfloat16* __restrict__ xb) {
  const int id = blockIdx.x;
  if (id >= 8192) {                     // x f32 -> bf16
    const size_t base = ((size_t)(id - 8192) * 256 + threadIdx.x) * 8;
    float4 a = *reinterpret_cast<const float4*>(x + base);
    float4 b = *reinterpret_cast<const float4*>(x + base + 4);
    bf16x8 o;
    o[0] = (__bf16)a.x; o[1] = (__bf16)a.y; o[2] = (__bf16)a.z; o[3] = (__bf16)a.w;
    o[4] = (__bf16)b.x; o[5] = (__bf16)b.y; o[6] = (__bf16)b.z; o[7] = (__bf16)b.w;
    *reinterpret_cast<bf16x8*>(xb + base) = o;
    return;
  }
  const float* W; __hip_bfloat16* WT; int K, N, kb, nb;
  if (id < 3072)      { W = w_qkv; WT = wqT; K = 1024; N = 3072; kb = id & 31;          nb = id >> 5; }
  else if (id < 4096) { W = w_out; WT = woT; K = 1024; N = 1024; kb = (id - 3072) & 31; nb = (id - 3072) >> 5; }
  else if (id < 6144) { W = w1;    WT = w1T; K = 1024; N = 2048; kb = (id - 4096) & 31; nb = (id - 4096) >> 5; }
  else                { W = w2;    WT = w2T; K = 2048; N = 1024; kb = (id - 6144) & 63; nb = (id - 6144) >> 6; }
  __shared__ float tsm[32][33];
  const int k0 = kb * 32, n0 = nb * 32;
  const int c = threadIdx.x & 31, r = threadIdx.x >> 5;
#pragma unroll
  for (int i = 0; i < 4; ++i)
    tsm[r + 8 * i][c] = W[(size_t)(k0 + r + 8 * i) * N + n0 + c];
  __syncthreads();
#pragma unroll
  for (int i = 0; i < 4; ++i)
    WT[(size_t)(n0 + r + 8 * i) * K + k0 + c] = __float2bfloat16(tsm[c][r + 8 * i]);
}

// ---------------- GEMM v2: BK=64, both-sides XOR swizzle, XCD block swizzle ----------------
// C = A[M,K] @ BT[N,K]^T. EPI: 0 none, 1 +bias, 2 +bias+gelu. OUTB: bf16/f32 out.
// HASRES: 0 none, 1 f32, 2 bf16. BN: 128 or 64.
// LDS layout: row-major [row][64 k], row stride 128B; chunk slot s of row r holds
// global k-chunk s^(r&7) (pre-swizzled GLD16 source); reads XOR the same term ->
// frag ds_read_b128 spreads rows over 8 banks (2-way, free).
template<int EPI, int OUTB, int HASRES, int BN>
__global__ __launch_bounds__(256) void gemm2(const __hip_bfloat16* __restrict__ A,
                                             const __hip_bfloat16* __restrict__ BT,
                                             const float* __restrict__ bias,
                                             float* __restrict__ Cf,
                                             __hip_bfloat16* __restrict__ Cb,
                                             const float* __restrict__ RESF,
                                             const __hip_bfloat16* __restrict__ RESB,
                                             int M, int N, int K) {
  constexpr int MI = (BN == 128) ? 4 : 2;
  __shared__ __align__(16) __hip_bfloat16 As[128 * 64];
  __shared__ __align__(16) __hip_bfloat16 Bs[BN * 64];
  const int tid  = threadIdx.x;
  const int lane = tid & 63, wave = tid >> 6;
  const int wr = (BN == 128) ? (wave >> 1) : wave;
  const int wc = (BN == 128) ? (wave & 1) : 0;
  const int lr = lane & 15, lq = lane >> 4;
  // bijective XCD swizzle (grid size is a multiple of 8 for all call sites)
  unsigned g = blockIdx.y * gridDim.x + blockIdx.x;
  const unsigned cpx = (gridDim.x * gridDim.y) >> 3;
  g = (g & 7) * cpx + (g >> 3);
  const int bm0 = (int)(g / gridDim.x) * 128;
  const int bn0 = (int)(g % gridDim.x) * BN;
  f32x4 acc[MI][4] = {};

  for (int k0 = 0; k0 < K; k0 += 64) {
#pragma unroll
    for (int j = 0; j < 4; ++j) {
      const int cbase = j * 256 + wave * 64;
      const int c = cbase + lane;
      const int row = c >> 3, slot = c & 7;
      GLD16(A + (size_t)(bm0 + row) * K + k0 + ((slot ^ (row & 7)) * 8),
            (char*)As + cbase * 16);
    }
#pragma unroll
    for (int j = 0; j < BN / 32; ++j) {
      const int cbase = j * 256 + wave * 64;
      const int c = cbase + lane;
      const int row = c >> 3, slot = c & 7;
      GLD16(BT + (size_t)(bn0 + row) * K + k0 + ((slot ^ (row & 7)) * 8),
            (char*)Bs + cbase * 16);
    }
    __syncthreads();
#pragma unroll
    for (int kk = 0; kk < 2; ++kk) {
      const int co = (kk * 64 + lq * 16) ^ ((lr & 7) << 4);
      bf16x8 af[MI], bfr[4];
#pragma unroll
      for (int i = 0; i < MI; ++i)
        af[i] = *reinterpret_cast<const bf16x8*>(
            (const char*)As + (wr * (MI * 16) + i * 16 + lr) * 128 + co);
#pragma unroll
      for (int i = 0; i < 4; ++i)
        bfr[i] = *reinterpret_cast<const bf16x8*>(
            (const char*)Bs + (wc * 64 + i * 16 + lr) * 128 + co);
#pragma unroll
      for (int mi = 0; mi < MI; ++mi)
#pragma unroll
        for (int ni = 0; ni < 4; ++ni)
          acc[mi][ni] = __builtin_amdgcn_mfma_f32_16x16x32_bf16(af[mi], bfr[ni], acc[mi][ni], 0, 0, 0);
    }
    __syncthreads();
  }

#pragma unroll
  for (int mi = 0; mi < MI; ++mi) {
#pragma unroll
    for (int ni = 0; ni < 4; ++ni) {
      const int col = bn0 + wc * 64 + ni * 16 + lr;
      const float bv = (EPI >= 1) ? bias[col] : 0.0f;
#pragma unroll
      for (int j = 0; j < 4; ++j) {
        const int row = bm0 + wr * (MI * 16) + mi * 16 + lq * 4 + j;
        float v = acc[mi][ni][j] + bv;
        if (HASRES == 1) v += RESF[(size_t)row * N + col];
        if (HASRES == 2) v += __bfloat162float(RESB[(size_t)row * N + col]);
        if (EPI == 2) v = 0.5f * v * (1.0f + erff(v * 0.70710678118654752f));
        if (OUTB) Cb[(size_t)row * N + col] = __float2bfloat16(v);
        else      Cf[(size_t)row * N + col] = v;
      }
    }
  }
}

// ---------------- causal flash attention (r6-verified v5) ----------------
// Block: 32 q-rows, 4 waves split-K round-robin (KVBLK=32), no in-loop barriers.
// Swapped QK (lane owns one q-row); K prefetched in regs one tile ahead;
// V staged ROW-major per wave via global_load_lds (async DMA, conflict-free);
// PV A-frags (V^T) via scalar ds_read_u16 (2-way, free). O^T partials merged at end.

#define DIAG_MASK(sv)                                                               \
  _Pragma("unroll")                                                                 \
  for (int r = 0; r < 16; ++r) {                                                    \
    const int kl = (r & 3) + 8 * (r >> 2) + 4 * hi;                                 \
    if (kl > lq32) sv[r] = -1e30f;                                                  \
  }

#define PV_HALF(wl0, wl1, wh0, wh1, ksg)                                            \
  {                                                                                 \
    unsigned t0_ = hi ? (wl0) : (wh0);                                              \
    unsigned t1_ = hi ? (wl1) : (wh1);                                              \
    t0_ = (unsigned)__shfl_xor((int)t0_, 32);                                       \
    t1_ = (unsigned)__shfl_xor((int)t1_, 32);                                       \
    u32x4 fw;                                                                       \
    fw[0] = hi ? t0_ : (wl0);  fw[1] = hi ? t1_ : (wl1);                            \
    fw[2] = hi ? (wh0) : t0_;  fw[3] = hi ? (wh1) : t1_;                            \
    bf16x8 pfb = __builtin_bit_cast(bf16x8, fw);                                    \
    const int krow_ = (ksg) * 16 + 8 * hi;                                          \
    bf16x8 vA, vB;                                                                  \
    _Pragma("unroll")                                                               \
    for (int j_ = 0; j_ < 8; ++j_) {                                                \
      vA[j_] = VwB[(krow_ + j_) * 64 + lq32];                                       \
      vB[j_] = VwB[(krow_ + j_) * 64 + 32 + lq32];                                  \
    }                                                                               \
    __builtin_amdgcn_s_setprio(1);                                                  \
    o0 = __builtin_amdgcn_mfma_f32_32x32x16_bf16(vA, pfb, o0, 0, 0, 0);             \
    o1 = __builtin_amdgcn_mfma_f32_32x32x16_bf16(vB, pfb, o1, 0, 0, 0);             \
    __builtin_amdgcn_s_setprio(0);                                                  \
  }

__global__ __launch_bounds__(256, 4) void attn_k(const __hip_bfloat16* __restrict__ qkv,
                                                 __hip_bfloat16* __restrict__ outb) {
  __shared__ __align__(16) char smem[4 * 8192 + 2048];
  // XCD-aware swizzle: xcd = bid%8 owns 4 heads; heavy q-blocks dispatched first
  const int bid = blockIdx.x;
  const int seq = bid >> 3;
  const int bh  = (bid & 7) * 4 + (seq & 3);     // 0..31
  const int qt32 = 63 - (seq >> 2);              // 0..63, heavy first
  const int b = bh >> 4, h = bh & 15;
  const int qb = qt32 * 32;
  const int tid = threadIdx.x;
  const int lane = tid & 63, wave = tid >> 6;
  const int lq32 = lane & 31, hi = lane >> 5;
  const size_t rowbase = (size_t)(b * L_SEQ) * QKV_LD;
  char* const Vw = smem + wave * 8192;           // wave slice: V rows (4KB) / O^T partials (8KB)
  const __bf16* const VwB = (const __bf16*)Vw;
  float* const ML = (float*)(smem + 32768);

  // Q B-frags: lane holds Q[qb+lq32][16c + 8hi + j]
  bf16x8 qf[4];
  {
    const __hip_bfloat16* qp = qkv + rowbase + (size_t)(qb + lq32) * QKV_LD + h * HDIM + 8 * hi;
#pragma unroll
    for (int c = 0; c < 4; ++c) qf[c] = *reinterpret_cast<const bf16x8*>(qp + 16 * c);
  }

  f32x16 o0 = {}, o1 = {};
  float m = -1e30f, lsum = 0.0f;

  int t = wave;
  bf16x8 kr0, kr1, kr2, kr3;
  if (t <= qt32) {                               // prime K regs for first tile
    const __hip_bfloat16* kp = qkv + rowbase + (size_t)(t * 32 + lq32) * QKV_LD + DM + h * HDIM + 8 * hi;
    kr0 = *reinterpret_cast<const bf16x8*>(kp);
    kr1 = *reinterpret_cast<const bf16x8*>(kp + 16);
    kr2 = *reinterpret_cast<const bf16x8*>(kp + 32);
    kr3 = *reinterpret_cast<const bf16x8*>(kp + 48);
  }

  for (; t <= qt32; t += 4) {
    const int k0 = t * 32;
    const bool pf = (t + 4 <= qt32);
    // ---- prefetch next K tile into regs (consumed next iter) ----
    bf16x8 kn0, kn1, kn2, kn3;
    if (pf) {
      const __hip_bfloat16* kp = qkv + rowbase + (size_t)(k0 + 128 + lq32) * QKV_LD + DM + h * HDIM + 8 * hi;
      kn0 = *reinterpret_cast<const bf16x8*>(kp);
      kn1 = *reinterpret_cast<const bf16x8*>(kp + 16);
      kn2 = *reinterpret_cast<const bf16x8*>(kp + 32);
      kn3 = *reinterpret_cast<const bf16x8*>(kp + 48);
    }
    // ---- V rows -> wave-private LDS via async DMA (linear, conflict-free) ----
#pragma unroll
    for (int p = 0; p < 4; ++p)
      GLD16(qkv + rowbase + (size_t)(k0 + 8 * p + (lane >> 3)) * QKV_LD + 2 * DM + h * HDIM + (lane & 7) * 8,
            Vw + p * 1024);
    // ---- QK ----
    f32x16 s = {};
    __builtin_amdgcn_s_setprio(1);
    s = __builtin_amdgcn_mfma_f32_32x32x16_bf16(kr0, qf[0], s, 0, 0, 0);
    s = __builtin_amdgcn_mfma_f32_32x32x16_bf16(kr1, qf[1], s, 0, 0, 0);
    s = __builtin_amdgcn_mfma_f32_32x32x16_bf16(kr2, qf[2], s, 0, 0, 0);
    s = __builtin_amdgcn_mfma_f32_32x32x16_bf16(kr3, qf[3], s, 0, 0, 0);
    __builtin_amdgcn_s_setprio(0);
    if (t == qt32) { DIAG_MASK(s) }
    // ---- online softmax (tree max, defer-rescale THR) ----
    float a0 = fmaxf(s[0], s[1]),   a1 = fmaxf(s[2], s[3]);
    float a2 = fmaxf(s[4], s[5]),   a3 = fmaxf(s[6], s[7]);
    float a4 = fmaxf(s[8], s[9]),   a5 = fmaxf(s[10], s[11]);
    float a6 = fmaxf(s[12], s[13]), a7 = fmaxf(s[14], s[15]);
    a0 = fmaxf(a0, a1); a2 = fmaxf(a2, a3); a4 = fmaxf(a4, a5); a6 = fmaxf(a6, a7);
    float tm = fmaxf(fmaxf(a0, a2), fmaxf(a4, a6));
    tm = fmaxf(tm, __shfl_xor(tm, 32));
    if (!__all(tm <= m + DTHR)) {
      const float mn = fmaxf(m, tm);
      const float fac = __builtin_amdgcn_exp2f((m - mn) * RL);
      m = mn; lsum *= fac; o0 *= fac; o1 *= fac;
    }
    const float mneg = -m * RL;
    float rs = 0.0f;
#pragma unroll
    for (int r = 0; r < 16; ++r) {
      s[r] = __builtin_amdgcn_exp2f(fmaf(s[r], RL, mneg));
      rs += s[r];
    }
    rs += __shfl_xor(rs, 32);
    lsum += rs;
    // ---- PV ----
    unsigned w0 = pack2(s[0], s[1]),   w1 = pack2(s[2], s[3]);
    unsigned w2 = pack2(s[4], s[5]),   w3 = pack2(s[6], s[7]);
    unsigned w4 = pack2(s[8], s[9]),   w5 = pack2(s[10], s[11]);
    unsigned w6 = pack2(s[12], s[13]), w7 = pack2(s[14], s[15]);
    PV_HALF(w0, w1, w2, w3, 0)
    PV_HALF(w4, w5, w6, w7, 1)
    if (pf) { kr0 = kn0; kr1 = kn1; kr2 = kn2; kr3 = kn3; }
  }

  // ---- write partials (O^T into own slice; m,l) ----
  {
    float* Ow = (float*)Vw;
#pragma unroll
    for (int r = 0; r < 16; ++r) {
      const int d0 = (r & 3) + 8 * (r >> 2) + 4 * hi;
      Ow[d0 * 32 + lq32] = o0[r];
      Ow[(d0 + 32) * 32 + lq32] = o1[r];
    }
    if (hi == 0) {
      ML[wave * 128 + lq32] = m;
      ML[wave * 128 + 64 + lq32] = lsum;
    }
  }
  __syncthreads();

  // ---- combine 4 partials; each thread: one q (tid&31), 8 d's ----
  {
    const int q = tid & 31, dg = tid >> 5;    // dg 0..7
    const float m0 = ML[q], m1 = ML[128 + q], m2 = ML[256 + q], m3 = ML[384 + q];
    const float M = fmaxf(fmaxf(m0, m1), fmaxf(m2, m3));
    const float c0 = __builtin_amdgcn_exp2f((m0 - M) * RL);
    const float c1 = __builtin_amdgcn_exp2f((m1 - M) * RL);
    const float c2 = __builtin_amdgcn_exp2f((m2 - M) * RL);
    const float c3 = __builtin_amdgcn_exp2f((m3 - M) * RL);
    const float l = c0 * ML[64 + q] + c1 * ML[192 + q] + c2 * ML[320 + q] + c3 * ML[448 + q];
    const float inv = 1.0f / l;
    const float* OB = (const float*)smem;
    bf16x8 ov;
#pragma unroll
    for (int i = 0; i < 8; ++i) {
      const int idx = (dg * 8 + i) * 32 + q;
      const float v = c0 * OB[idx] + c1 * OB[2048 + idx] + c2 * OB[4096 + idx] + c3 * OB[6144 + idx];
      ov[i] = (__bf16)(v * inv);
    }
    *reinterpret_cast<bf16x8*>(outb + (size_t)(b * L_SEQ + qb + q) * DM + h * HDIM + dg * 8) = ov;
  }
}

// ---------------- LayerNorm: Y = LN(X) * g + be. MODE 0: f32 out, 2: bf16 out only ----
template<int MODE>
__global__ __launch_bounds__(256) void ln_k(const float* __restrict__ X,
                                            const float* __restrict__ g,
                                            const float* __restrict__ be,
                                            float* __restrict__ Y,
                                            __hip_bfloat16* __restrict__ Yb) {
  const int row = blockIdx.x;
  const int tid = threadIdx.x;
  const int lane = tid & 63, wave = tid >> 6;
  float4 x4 = *reinterpret_cast<const float4*>(X + (size_t)row * DM + tid * 4);
  float v0 = x4.x, v1 = x4.y, v2 = x4.z, v3 = x4.w;
  float s  = v0 + v1 + v2 + v3;
  float ss = v0 * v0 + v1 * v1 + v2 * v2 + v3 * v3;
#pragma unroll
  for (int off = 1; off < 64; off <<= 1) {
    s  += __shfl_xor(s, off);
    ss += __shfl_xor(ss, off);
  }
  __shared__ float red[8];
  if (lane == 0) { red[wave] = s; red[4 + wave] = ss; }
  __syncthreads();
  float S  = red[0] + red[1] + red[2] + red[3];
  float SS = red[4] + red[5] + red[6] + red[7];
  float mu  = S * (1.0f / DM);
  float var = SS * (1.0f / DM) - mu * mu;
  float rsd = rsqrtf(var + 1e-5f);
  float4 gv = *reinterpret_cast<const float4*>(g + tid * 4);
  float4 bv = *reinterpret_cast<const float4*>(be + tid * 4);
  float4 y;
  y.x = (v0 - mu) * rsd * gv.x + bv.x;
  y.y = (v1 - mu) * rsd * gv.y + bv.y;
  y.z = (v2 - mu) * rsd * gv.z + bv.z;
  y.w = (v3 - mu) * rsd * gv.w + bv.w;
  if (MODE != 2)
    *reinterpret_cast<float4*>(Y + (size_t)row * DM + tid * 4) = y;
  if (MODE == 2) {
    bf16x4 yb;
    yb[0] = (__bf16)y.x; yb[1] = (__bf16)y.y; yb[2] = (__bf16)y.z; yb[3] = (__bf16)y.w;
    *reinterpret_cast<bf16x4*>(Yb + (size_t)row * DM + tid * 4) = yb;
  }
}

extern "C" void kernel_launch(void* const* d_in, const int* in_sizes, int n_in,
                              void* d_out, int out_size, void* d_ws, size_t ws_size,
                              hipStream_t stream) {
  const float* x     = (const float*)d_in[0];
  const float* w_qkv = (const float*)d_in[1];
  const float* w_out = (const float*)d_in[2];
  const float* w1    = (const float*)d_in[3];
  const float* b1    = (const float*)d_in[4];
  const float* w2    = (const float*)d_in[5];
  const float* b2    = (const float*)d_in[6];
  const float* g1    = (const float*)d_in[7];
  const float* be1   = (const float*)d_in[8];
  const float* g2    = (const float*)d_in[9];
  const float* be2   = (const float*)d_in[10];
  float* outp = (float*)d_out;
  char* base  = (char*)d_ws;
  const int M = NB * L_SEQ;                 // 4096

  __hip_bfloat16* w2T  = (__hip_bfloat16*)(base + 0);          // [1024][2048]
  __hip_bfloat16* woT  = (__hip_bfloat16*)(base + 4194304);    // [1024][1024]
  __hip_bfloat16* w1T  = (__hip_bfloat16*)(base + 6291456);    // [2048][1024]
  __hip_bfloat16* wqT  = (__hip_bfloat16*)(base + 10485760);   // [3072][1024]
  __hip_bfloat16* xb   = (__hip_bfloat16*)(base + 16777216);   // [4096][1024]
  __hip_bfloat16* attnb= xb;                                   // reuse after qkv GEMM
  __hip_bfloat16* qkvb = (__hip_bfloat16*)(base + 25165824);   // [4096][3072]
  __hip_bfloat16* ffh  = (__hip_bfloat16*)(base + 25165824);   // [4096][2048] (qkvb dead)
  __hip_bfloat16* ln1b = (__hip_bfloat16*)(base + 41943040);   // [4096][1024] (qkvb dead)
  float*          ffo  = (float*)(base + 8388608);             // [4096][1024] f32 (dead wts+xb)
  float*          proj = outp;                                 // d_out as scratch

  // fused prep: all weight transposes + x convert
  prep_k<<<10240, 256, 0, stream>>>(w_qkv, w_out, w1, w2, x, wqT, woT, w1T, w2T, xb);

  // 1. qkv = x @ w_qkv (bf16)
  gemm2<0, 1, 0, 128><<<dim3(24, 32), 256, 0, stream>>>(xb, wqT, nullptr, nullptr, qkvb, nullptr, nullptr, M, QKV_LD, DM);
  // 2. attention (bf16): 64 q-blocks x 32 bh, XCD-swizzled
  attn_k<<<2048, 256, 0, stream>>>(qkvb, attnb);
  // 3. proj = attn @ w_out + x  (f32, residual fused; BN=64)
  gemm2<0, 0, 1, 64><<<dim3(16, 32), 256, 0, stream>>>(attnb, woT, nullptr, proj, nullptr, x, nullptr, M, DM, DM);
  // 4. ln1 = LN(proj)  (bf16 only)
  ln_k<2><<<M, 256, 0, stream>>>(proj, g1, be1, nullptr, ln1b);
  // 5. ffh = gelu(ln1 @ w1 + b1) (bf16)
  gemm2<2, 1, 0, 128><<<dim3(16, 32), 256, 0, stream>>>(ln1b, w1T, b1, nullptr, ffh, nullptr, nullptr, M, 2 * DM, DM);
  // 6. ffo = ffh @ w2 + b2 + ln1 (f32; bf16 residual; BN=64)
  gemm2<1, 0, 2, 64><<<dim3(16, 32), 256, 0, stream>>>(ffh, w2T, b2, ffo, nullptr, nullptr, ln1b, M, DM, 2 * DM);
  // 7. out = LN(ffo)
  ln_k<0><<<M, 256, 0, stream>>>(ffo, g2, be2, outp, nullptr);
}